// Round 7
// baseline (487.904 us; speedup 1.0000x reference)
//
#include <hip/hip_runtime.h>

typedef unsigned short u16;
typedef __bf16 bfx8 __attribute__((ext_vector_type(8)));
typedef float f32x4 __attribute__((ext_vector_type(4)));
typedef unsigned short u16x4 __attribute__((ext_vector_type(4)));

#define NN 1024
#define FF 64
#define NSLICE 32
#define KFEAT 11

// ---- workspace layout ----
#define POOL_BYTES (NSLICE * KFEAT * FF * 4)  // 90112
#define MSUM_OFF   POOL_BYTES
#define SLICE0     ((size_t)1 << 20)
#define MB1        (1024u * 1024u)
#define KB128      (131072u)
#define KB256      (262144u)
// bf16 NxN matrices
#define OFF_P    0u
#define OFF_PT   (2u * MB1)
#define OFF_P2   (4u * MB1)
#define OFF_P2T  (6u * MB1)
#define OFF_P4   (8u * MB1)
// bf16 [64][1024] transposed narrow operands
#define OFF_XT   (10u * MB1)
#define OFF_Y4T  (10u * MB1 + 1u * KB128)
#define OFF_Y8T  (10u * MB1 + 2u * KB128)
#define OFF_Y12T (10u * MB1 + 3u * KB128)
#define OFF_S1T  (10u * MB1 + 4u * KB128)
#define OFF_S2T  (10u * MB1 + 5u * KB128)
#define OFF_S3T  (10u * MB1 + 6u * KB128)
#define OFF_WT   (10u * MB1 + 7u * KB128)
// f32 [1024][64] narrow results
#define OFF_Y1   (11u * MB1)
#define OFF_Y2   (11u * MB1 + 1u * KB256)
#define OFF_Y4   (11u * MB1 + 2u * KB256)
#define OFF_Y8   (11u * MB1 + 3u * KB256)
#define OFF_PS1  (11u * MB1 + 4u * KB256)
#define OFF_PS2  (11u * MB1 + 5u * KB256)
#define OFF_PS3  (11u * MB1 + 6u * KB256)
#define OFF_QS1  (11u * MB1 + 7u * KB256)
#define OFF_QS2  (11u * MB1 + 8u * KB256)
#define OFF_QS3  (11u * MB1 + 9u * KB256)
#define OFF_W    (11u * MB1 + 10u * KB256)
#define PS_BYTES ((size_t)(14u * MB1))

// async global->LDS, 16B per lane; LDS dest = wave-uniform base + lane*16
#define GL16(g, l) __builtin_amdgcn_global_load_lds( \
    (const __attribute__((address_space(1))) unsigned int*)(g), \
    (__attribute__((address_space(3))) unsigned int*)(l), 16, 0, 0)

// Bank-conflict-free chunk rotation (rule #21): linear LDS dest, permuted
// global source chunk (c - (tid>>3))&3, matching permuted read rotation
// ((lk + (l16>>1))&3). Verified: conflict counter 9.17M -> 0.79M.

__device__ __forceinline__ u16 f2b(float v) {
  __bf16 h = (__bf16)v;
  return __builtin_bit_cast(u16, h);
}

// ---- P slice: f32 -> bf16 row-major (P) + bf16 transposed (PT) ----
__global__ void k_convP(const float* __restrict__ P, char* ws, int sliceBase) {
  __shared__ float tile[64][65];
  int s = blockIdx.z;
  const float* Ps = P + (size_t)(sliceBase + s) * NN * NN;
  char* base = ws + SLICE0 + (size_t)s * PS_BYTES;
  u16* Pb  = (u16*)(base + OFF_P);
  u16* PbT = (u16*)(base + OFF_PT);
  int r0 = blockIdx.y * 64, c0 = blockIdx.x * 64;
  int tid = threadIdx.x;
  int tc = tid & 15, tr = tid >> 4;
  for (int rr = 0; rr < 64; rr += 16) {
    int r = rr + tr;
    float4 v = *(const float4*)&Ps[(size_t)(r0 + r) * NN + c0 + tc * 4];
    tile[r][tc * 4 + 0] = v.x;
    tile[r][tc * 4 + 1] = v.y;
    tile[r][tc * 4 + 2] = v.z;
    tile[r][tc * 4 + 3] = v.w;
    u16x4 pk = {f2b(v.x), f2b(v.y), f2b(v.z), f2b(v.w)};
    *(u16x4*)&Pb[(size_t)(r0 + r) * NN + c0 + tc * 4] = pk;
  }
  __syncthreads();
  for (int it = 0; it < 4; ++it) {
    int oc = (tid >> 4) + it * 16;
    int ch = tid & 15;
    u16x4 pk = {f2b(tile[ch * 4 + 0][oc]), f2b(tile[ch * 4 + 1][oc]),
                f2b(tile[ch * 4 + 2][oc]), f2b(tile[ch * 4 + 3][oc])};
    *(u16x4*)&PbT[(size_t)(c0 + oc) * NN + r0 + ch * 4] = pk;
  }
}

// ---- X slice: f32 [1024][64] -> bf16 XT [64][1024] ----
__global__ void k_convX(const float* __restrict__ X, char* ws, int sliceBase) {
  __shared__ float tile[64][65];
  int s = blockIdx.z;
  const float* Xs = X + (size_t)(sliceBase + s) * NN * FF;
  u16* XT = (u16*)(ws + SLICE0 + (size_t)s * PS_BYTES + OFF_XT);
  int r0 = blockIdx.x * 64;
  int tx = threadIdx.x & 63, ty = threadIdx.x >> 6;
  for (int rr = 0; rr < 64; rr += 4)
    tile[rr + ty][tx] = Xs[(size_t)(r0 + rr + ty) * FF + tx];
  __syncthreads();
  for (int rr = 0; rr < 64; rr += 4)
    XT[(size_t)(rr + ty) * NN + r0 + tx] = f2b(tile[tx][rr + ty]);
}

__global__ void k_msum(const float* __restrict__ mask, float* msum) {
  int s = blockIdx.x;
  const float* m = mask + (size_t)s * NN;
  int t = threadIdx.x;
  float v = m[t] + m[t + 256] + m[t + 512] + m[t + 768];
  for (int o = 32; o; o >>= 1) v += __shfl_down(v, o);
  __shared__ float ps[4];
  if ((t & 63) == 0) ps[t >> 6] = v;
  __syncthreads();
  if (t == 0) msum[s] = ps[0] + ps[1] + ps[2] + ps[3];
}

// ---- squaring GEMM: C = A @ B (B given transposed). Writes C bf16 and
// optionally C^T (offT>=0). 128x128 tile, BK=32, 4 waves, global_load_lds,
// XCD swizzle, chunk-rotation LDS, counted-vmcnt double-buffer pipeline.
// launch_bounds(.,3): 3 waves/EU -> 3 blocks/CU (148 unified regs <= 168 cap).
__global__ __launch_bounds__(256, 3)
void k_square(char* ws, int offA, int offB, int offC, int offT) {
  __shared__ u16 sh[16384];  // 32KB: A bufs @0/4096, B bufs @8192/12288

  unsigned nwg = gridDim.x, wg = blockIdx.x;
  unsigned newid = (wg & 7) * (nwg >> 3) + (wg >> 3);  // slice-per-XCD
  int z = newid >> 6;
  int by = (newid >> 3) & 7, bx = newid & 7;

  char* base = ws + SLICE0 + (size_t)z * PS_BYTES;
  const u16* A  = (const u16*)(base + offA);
  const u16* Bt = (const u16*)(base + offB);
  u16* C        = (u16*)(base + offC);

  const int tid = threadIdx.x;
  const int lane = tid & 63, wave = tid >> 6;
  const int wr = wave >> 1, wc = wave & 1;
  const int l16 = lane & 15, lk = lane >> 4;
  const int bm = by * 128, bn = bx * 128;

  const int pc = (((tid & 3) - (tid >> 3)) & 3) << 3;
  const u16* gA = A + (size_t)(bm + (tid >> 2)) * NN + pc;
  const u16* gB = Bt + (size_t)(bn + (tid >> 2)) * NN + pc;
  const int rot = ((lk + (l16 >> 1)) & 3) << 3;

  f32x4 acc[4][4] = {};

#define SQ_STAGE(k0, buf)                                   \
  {                                                         \
    u16* dA = sh + (buf)*4096 + wave * 512;                 \
    u16* dB = sh + 8192 + (buf)*4096 + wave * 512;          \
    GL16(gA + (k0), dA);                                    \
    GL16(gA + 64 * NN + (k0), dA + 2048);                   \
    GL16(gB + (k0), dB);                                    \
    GL16(gB + 64 * NN + (k0), dB + 2048);                   \
  }

#define SQ_COMPUTE(buf)                                                      \
  {                                                                          \
    const u16* bA = sh + (buf)*4096;                                         \
    const u16* bB = sh + 8192 + (buf)*4096;                                  \
    bfx8 af[4], bf[4];                                                       \
    _Pragma("unroll") for (int m = 0; m < 4; ++m)                            \
        af[m] = *(const bfx8*)&bA[(wr * 64 + m * 16 + l16) * 32 + rot];      \
    _Pragma("unroll") for (int n = 0; n < 4; ++n)                            \
        bf[n] = *(const bfx8*)&bB[(wc * 64 + n * 16 + l16) * 32 + rot];      \
    __builtin_amdgcn_s_setprio(1);                                           \
    _Pragma("unroll") for (int m = 0; m < 4; ++m)                            \
        _Pragma("unroll") for (int n = 0; n < 4; ++n)                        \
            acc[m][n] = __builtin_amdgcn_mfma_f32_16x16x32_bf16(             \
                af[m], bf[n], acc[m][n], 0, 0, 0);                           \
    __builtin_amdgcn_s_setprio(0);                                           \
  }

  SQ_STAGE(0, 0);
#pragma unroll 2
  for (int t = 1; t < 32; ++t) {
    SQ_STAGE(t * 32, t & 1);
    asm volatile("s_waitcnt vmcnt(4)" ::: "memory");  // own tile t-1 done
    __builtin_amdgcn_s_barrier();                     // -> globally done
    SQ_COMPUTE((t - 1) & 1);
    __builtin_amdgcn_s_barrier();                     // reads done
  }
  asm volatile("s_waitcnt vmcnt(0)" ::: "memory");
  __builtin_amdgcn_s_barrier();
  SQ_COMPUTE(1);

  // C store (bf16 scalar)
#pragma unroll
  for (int m = 0; m < 4; ++m) {
    int row0 = bm + wr * 64 + m * 16 + lk * 4;
#pragma unroll
    for (int n = 0; n < 4; ++n) {
      int col = bn + wc * 64 + n * 16 + l16;
#pragma unroll
      for (int r = 0; r < 4; ++r)
        C[(size_t)(row0 + r) * NN + col] = f2b(acc[m][n][r]);
    }
  }

  // C^T via per-wave LDS bounce: 4 passes of 16 out-rows, 16B stores
  if (offT >= 0) {
    u16* T = (u16*)(base + offT);
    u16* reg = sh + wave * 1152;  // [16][72] u16, 16B-aligned rows
#pragma unroll
    for (int n = 0; n < 4; ++n) {
      __syncthreads();
#pragma unroll
      for (int m = 0; m < 4; ++m) {
        u16x4 pk = {f2b(acc[m][n][0]), f2b(acc[m][n][1]),
                    f2b(acc[m][n][2]), f2b(acc[m][n][3])};
        *(u16x4*)&reg[l16 * 72 + m * 16 + lk * 4] = pk;
      }
      __syncthreads();
#pragma unroll
      for (int h = 0; h < 2; ++h) {
        int row = (lane >> 3) + 8 * h;
        int c8 = lane & 7;
        uint4 v = *(const uint4*)&reg[row * 72 + c8 * 8];
        *(uint4*)&T[(size_t)(bn + wc * 64 + n * 16 + row) * NN + bm + wr * 64 + c8 * 8] = v;
      }
    }
  }
}

// ---- unified narrow GEMM: acc[64x64 tile] = A[1024x1024] @ Bt_sub[64][1024].
// M-split: 16 blocks of 64 rows per (slice,sub) -> 2+ blocks/CU for barrier
// overlap. 4 waves (2Mx2N), per-wave 32x32, acc[2][2]. LDS 16KB dbuf.
struct NA {
  int a, nsub, rawK;
  int bt0, bt1, bt2;
  int d0, d1, d2;
  int pk0, pk1, pk2;
  int f0, f1, f2;
  int ta0, ta1, ta2;
  int tv0, tv1, tv2;
};

__global__ __launch_bounds__(256)
void k_nar(char* ws, int sliceBase, float* __restrict__ pooled, NA na) {
  __shared__ u16 sh[8192];  // 16KB: A bufs @0/2048, B bufs @4096/6144
  unsigned nwg = gridDim.x, wg = blockIdx.x;
  unsigned newid = (wg & 7) * (nwg >> 3) + (wg >> 3);
  int by = newid & 15;
  int rest = newid >> 4;
  int sub = rest % na.nsub;
  int s = rest / na.nsub;
  char* base = ws + SLICE0 + (size_t)s * PS_BYTES;

  int bt  = sub == 0 ? na.bt0 : (sub == 1 ? na.bt1 : na.bt2);
  int dof = sub == 0 ? na.d0  : (sub == 1 ? na.d1  : na.d2);
  int pk  = sub == 0 ? na.pk0 : (sub == 1 ? na.pk1 : na.pk2);
  int fo  = sub == 0 ? na.f0  : (sub == 1 ? na.f1  : na.f2);
  int tao = sub == 0 ? na.ta0 : (sub == 1 ? na.ta1 : na.ta2);
  int tvo = sub == 0 ? na.tv0 : (sub == 1 ? na.tv1 : na.tv2);

  const u16* A  = (const u16*)(base + na.a);
  const u16* Bt = (const u16*)(base + bt);
  int poolBase = (sliceBase + s) * (KFEAT * FF);

  const int tid = threadIdx.x;
  const int lane = tid & 63, wave = tid >> 6;
  const int wr = wave >> 1, wc = wave & 1;
  const int l16 = lane & 15, lk = lane >> 4;
  const int bm = by * 64;

  const int pc = (((tid & 3) - (tid >> 3)) & 3) << 3;
  const u16* gA = A + (size_t)(bm + (tid >> 2)) * NN + pc;
  const u16* gB = Bt + (size_t)(tid >> 2) * NN + pc;
  const int rot = ((lk + (l16 >> 1)) & 3) << 3;

  f32x4 acc[2][2] = {};

#define FT_STAGE(k0, buf)                                   \
  {                                                         \
    u16* dA = sh + (buf)*2048 + wave * 512;                 \
    u16* dB = sh + 4096 + (buf)*2048 + wave * 512;          \
    GL16(gA + (k0), dA);                                    \
    GL16(gB + (k0), dB);                                    \
  }

#define FT_COMPUTE(buf)                                                      \
  {                                                                          \
    const u16* bA = sh + (buf)*2048;                                         \
    const u16* bB = sh + 4096 + (buf)*2048;                                  \
    bfx8 af[2], bfr[2];                                                      \
    _Pragma("unroll") for (int m = 0; m < 2; ++m)                            \
        af[m] = *(const bfx8*)&bA[(wr * 32 + m * 16 + l16) * 32 + rot];      \
    _Pragma("unroll") for (int n = 0; n < 2; ++n)                            \
        bfr[n] = *(const bfx8*)&bB[(wc * 32 + n * 16 + l16) * 32 + rot];     \
    __builtin_amdgcn_s_setprio(1);                                           \
    _Pragma("unroll") for (int m = 0; m < 2; ++m)                            \
        _Pragma("unroll") for (int n = 0; n < 2; ++n)                        \
            acc[m][n] = __builtin_amdgcn_mfma_f32_16x16x32_bf16(             \
                af[m], bfr[n], acc[m][n], 0, 0, 0);                          \
    __builtin_amdgcn_s_setprio(0);                                           \
  }

  FT_STAGE(0, 0);
#pragma unroll 2
  for (int t = 1; t < 32; ++t) {
    FT_STAGE(t * 32, t & 1);
    asm volatile("s_waitcnt vmcnt(2)" ::: "memory");
    __builtin_amdgcn_s_barrier();
    FT_COMPUTE((t - 1) & 1);
    __builtin_amdgcn_s_barrier();
  }
  asm volatile("s_waitcnt vmcnt(0)" ::: "memory");
  __builtin_amdgcn_s_barrier();
  FT_COMPUTE(1);

  const float* D = dof >= 0 ? (const float*)(base + dof) : nullptr;
  float* F  = fo  >= 0 ? (float*)(base + fo)  : nullptr;
  u16* Ta   = tao >= 0 ? (u16*)(base + tao)   : nullptr;
  u16* Tv   = tvo >= 0 ? (u16*)(base + tvo)   : nullptr;

  float ps[2] = {0.f, 0.f};
  float pr[2] = {0.f, 0.f};

#pragma unroll
  for (int m = 0; m < 2; ++m) {
    int row0 = bm + wr * 32 + m * 16 + lk * 4;
#pragma unroll
    for (int n = 0; n < 2; ++n) {
      int col = wc * 32 + n * 16 + l16;
      float v0 = acc[m][n][0], v1 = acc[m][n][1], v2 = acc[m][n][2], v3 = acc[m][n][3];
      float w0 = v0, w1 = v1, w2 = v2, w3 = v3;
      if (D) {
        w0 = v0 - D[(size_t)(row0 + 0) * FF + col];
        w1 = v1 - D[(size_t)(row0 + 1) * FF + col];
        w2 = v2 - D[(size_t)(row0 + 2) * FF + col];
        w3 = v3 - D[(size_t)(row0 + 3) * FF + col];
      }
      float a0 = fabsf(w0), a1 = fabsf(w1), a2 = fabsf(w2), a3 = fabsf(w3);
      if (pk >= 0) ps[n] += a0 + a1 + a2 + a3;
      if (na.rawK >= 0) pr[n] += v0 + v1 + v2 + v3;
      if (F) {
        F[(size_t)(row0 + 0) * FF + col] = v0;
        F[(size_t)(row0 + 1) * FF + col] = v1;
        F[(size_t)(row0 + 2) * FF + col] = v2;
        F[(size_t)(row0 + 3) * FF + col] = v3;
      }
      if (Ta) {
        u16x4 pkk = {f2b(a0), f2b(a1), f2b(a2), f2b(a3)};
        *(u16x4*)&Ta[(size_t)col * NN + row0] = pkk;
      }
      if (Tv) {
        u16x4 pkk = {f2b(v0), f2b(v1), f2b(v2), f2b(v3)};
        *(u16x4*)&Tv[(size_t)col * NN + row0] = pkk;
      }
    }
  }

  if (pk >= 0) {
#pragma unroll
    for (int n = 0; n < 2; ++n) {
      float v = ps[n];
      v += __shfl_xor(v, 16);
      v += __shfl_xor(v, 32);
      if (lane < 16)
        atomicAdd(&pooled[poolBase + pk * FF + wc * 32 + n * 16 + lane], v);
    }
  }
  if (na.rawK >= 0) {
#pragma unroll
    for (int n = 0; n < 2; ++n) {
      float v = pr[n];
      v += __shfl_xor(v, 16);
      v += __shfl_xor(v, 32);
      if (lane < 16)
        atomicAdd(&pooled[poolBase + na.rawK * FF + wc * 32 + n * 16 + lane], v);
    }
  }
}

__global__ void k_final(const float* __restrict__ pooled, const float* __restrict__ msum,
                        float* __restrict__ out, int total) {
  int i = blockIdx.x * 256 + threadIdx.x;
  if (i < total) out[i] = pooled[i] / msum[i / (KFEAT * FF)];
}

static inline NA mkNA(int a, int nsub, int rawK,
                      int bt0, int bt1, int bt2, int d0, int d1, int d2,
                      int pk0, int pk1, int pk2, int f0, int f1, int f2,
                      int ta0, int ta1, int ta2, int tv0, int tv1, int tv2) {
  NA x;
  x.a = a; x.nsub = nsub; x.rawK = rawK;
  x.bt0 = bt0; x.bt1 = bt1; x.bt2 = bt2;
  x.d0 = d0; x.d1 = d1; x.d2 = d2;
  x.pk0 = pk0; x.pk1 = pk1; x.pk2 = pk2;
  x.f0 = f0; x.f1 = f1; x.f2 = f2;
  x.ta0 = ta0; x.ta1 = ta1; x.ta2 = ta2;
  x.tv0 = tv0; x.tv1 = tv1; x.tv2 = tv2;
  return x;
}

extern "C" void kernel_launch(void* const* d_in, const int* in_sizes, int n_in,
                              void* d_out, int out_size, void* d_ws, size_t ws_size,
                              hipStream_t stream) {
  const float* P = (const float*)d_in[0];
  const float* X = (const float*)d_in[1];
  const float* mask = (const float*)d_in[2];
  float* out = (float*)d_out;
  char* ws = (char*)d_ws;
  float* pooled = (float*)ws;
  float* msum = (float*)(ws + MSUM_OFF);

  hipMemsetAsync(pooled, 0, POOL_BYTES, stream);
  k_msum<<<NSLICE, 256, 0, stream>>>(mask, msum);

  int S = 1;
  if (ws_size > SLICE0 + PS_BYTES) S = (int)((ws_size - SLICE0) / PS_BYTES);
  if (S > NSLICE) S = NSLICE;
  if (S < 1) S = 1;

  for (int b0 = 0; b0 < NSLICE; b0 += S) {
    int n = (NSLICE - b0 < S) ? (NSLICE - b0) : S;
    k_convP<<<dim3(16, 16, n), 256, 0, stream>>>(P, ws, b0);
    k_convX<<<dim3(16, 1, n), 256, 0, stream>>>(X, ws, b0);
    // P2 = P@P (+P2^T), P4 = P2@P2
    k_square<<<64 * n, 256, 0, stream>>>(ws, OFF_P, OFF_PT, OFF_P2, (int)OFF_P2T);
    k_square<<<64 * n, 256, 0, stream>>>(ws, OFF_P2, OFF_P2T, OFF_P4, -1);
    // Y1 = P X
    NA a1 = mkNA(OFF_P, 1, -1, OFF_XT, -1, -1, -1, -1, -1, -1, -1, -1,
                 OFF_Y1, -1, -1, -1, -1, -1, -1, -1, -1);
    k_nar<<<16 * n, 256, 0, stream>>>(ws, b0, pooled, a1);
    // Y2 = P2 X ; s0 = |Y2-Y1| pool k=1
    NA a2 = mkNA(OFF_P2, 1, -1, OFF_XT, -1, -1, (int)OFF_Y1, -1, -1, 1, -1, -1,
                 OFF_Y2, -1, -1, -1, -1, -1, -1, -1, -1);
    k_nar<<<16 * n, 256, 0, stream>>>(ws, b0, pooled, a2);
    // Y4 = P4 X ; s1 = |Y4-Y2| pool k=2, s1T ; Y4 f32 + Y4T
    NA a3 = mkNA(OFF_P4, 1, -1, OFF_XT, -1, -1, (int)OFF_Y2, -1, -1, 2, -1, -1,
                 OFF_Y4, -1, -1, OFF_S1T, -1, -1, OFF_Y4T, -1, -1);
    k_nar<<<16 * n, 256, 0, stream>>>(ws, b0, pooled, a3);
    // Y8 = P4 Y4 ; s2 = |Y8-Y4| pool k=3, s2T ; Y8 f32 + Y8T
    NA a4 = mkNA(OFF_P4, 1, -1, OFF_Y4T, -1, -1, (int)OFF_Y4, -1, -1, 3, -1, -1,
                 OFF_Y8, -1, -1, OFF_S2T, -1, -1, OFF_Y8T, -1, -1);
    k_nar<<<16 * n, 256, 0, stream>>>(ws, b0, pooled, a4);
    // Y12 = P4 Y8 -> Y12T
    NA a5 = mkNA(OFF_P4, 1, -1, OFF_Y8T, -1, -1, -1, -1, -1, -1, -1, -1,
                 -1, -1, -1, -1, -1, -1, OFF_Y12T, -1, -1);
    k_nar<<<16 * n, 256, 0, stream>>>(ws, b0, pooled, a5);
    // Y16 = P4 Y12 ; s3 = |Y16-Y8| pool k=4, s3T ; F0 raw pool k=0
    NA a6 = mkNA(OFF_P4, 1, 0, OFF_Y12T, -1, -1, (int)OFF_Y8, -1, -1, 4, -1, -1,
                 -1, -1, -1, OFF_S3T, -1, -1, -1, -1, -1);
    k_nar<<<16 * n, 256, 0, stream>>>(ws, b0, pooled, a6);
    // P*{s1,s2,s3} -> f32
    NA a7 = mkNA(OFF_P, 3, -1, OFF_S1T, OFF_S2T, OFF_S3T, -1, -1, -1,
                 -1, -1, -1, OFF_PS1, OFF_PS2, OFF_PS3,
                 -1, -1, -1, -1, -1, -1);
    k_nar<<<48 * n, 256, 0, stream>>>(ws, b0, pooled, a7);
    // P2*{s1,s2,s3} ; |psi0 s_i| pools k=5,6,8 ; keep f32 for psi1
    NA a8 = mkNA(OFF_P2, 3, -1, OFF_S1T, OFF_S2T, OFF_S3T,
                 (int)OFF_PS1, (int)OFF_PS2, (int)OFF_PS3, 5, 6, 8,
                 OFF_QS1, OFF_QS2, OFF_QS3, -1, -1, -1, -1, -1, -1);
    k_nar<<<48 * n, 256, 0, stream>>>(ws, b0, pooled, a8);
    // P4*{s2,s3} ; |psi1 s_i| pools k=7,9 ; W = P4 s3 (f32 + WT)
    NA a9 = mkNA(OFF_P4, 2, -1, OFF_S2T, OFF_S3T, -1,
                 (int)OFF_QS2, (int)OFF_QS3, -1, 7, 9, -1,
                 -1, OFF_W, -1, -1, -1, -1, -1, OFF_WT, -1);
    k_nar<<<32 * n, 256, 0, stream>>>(ws, b0, pooled, a9);
    // P4*W ; |psi2 s3| pool k=10
    NA a10 = mkNA(OFF_P4, 1, -1, OFF_WT, -1, -1, (int)OFF_W, -1, -1, 10, -1, -1,
                  -1, -1, -1, -1, -1, -1, -1, -1, -1);
    k_nar<<<16 * n, 256, 0, stream>>>(ws, b0, pooled, a10);
  }
  int total = NSLICE * KFEAT * FF;
  k_final<<<(total + 255) / 256, 256, 0, stream>>>(pooled, msum, out, total);
}

// Round 8
// 480.987 us; speedup vs baseline: 1.0144x; 1.0144x over previous
//
#include <hip/hip_runtime.h>

typedef unsigned short u16;
typedef __bf16 bfx8 __attribute__((ext_vector_type(8)));
typedef float f32x4 __attribute__((ext_vector_type(4)));
typedef unsigned short u16x4 __attribute__((ext_vector_type(4)));

#define NN 1024
#define FF 64
#define NSLICE 32
#define KFEAT 11

// ---- workspace layout ----
#define POOL_BYTES (NSLICE * KFEAT * FF * 4)  // 90112
#define MSUM_OFF   POOL_BYTES
#define SLICE0     ((size_t)1 << 20)
#define MB1        (1024u * 1024u)
#define KB128      (131072u)
#define KB256      (262144u)
// bf16 NxN matrices
#define OFF_P    0u
#define OFF_PT   (2u * MB1)
#define OFF_P2   (4u * MB1)
#define OFF_P2T  (6u * MB1)
#define OFF_P4   (8u * MB1)
// bf16 [64][1024] transposed narrow operands
#define OFF_XT   (10u * MB1)
#define OFF_Y4T  (10u * MB1 + 1u * KB128)
#define OFF_Y8T  (10u * MB1 + 2u * KB128)
#define OFF_Y12T (10u * MB1 + 3u * KB128)
#define OFF_S1T  (10u * MB1 + 4u * KB128)
#define OFF_S2T  (10u * MB1 + 5u * KB128)
#define OFF_S3T  (10u * MB1 + 6u * KB128)
#define OFF_WT   (10u * MB1 + 7u * KB128)
// f32 [1024][64] narrow results
#define OFF_Y1   (11u * MB1)
#define OFF_Y2   (11u * MB1 + 1u * KB256)
#define OFF_Y4   (11u * MB1 + 2u * KB256)
#define OFF_Y8   (11u * MB1 + 3u * KB256)
#define OFF_PS1  (11u * MB1 + 4u * KB256)
#define OFF_PS2  (11u * MB1 + 5u * KB256)
#define OFF_PS3  (11u * MB1 + 6u * KB256)
#define OFF_QS1  (11u * MB1 + 7u * KB256)
#define OFF_QS2  (11u * MB1 + 8u * KB256)
#define OFF_QS3  (11u * MB1 + 9u * KB256)
#define OFF_W    (11u * MB1 + 10u * KB256)
#define PS_BYTES ((size_t)(14u * MB1))

// async global->LDS, 16B per lane; LDS dest = wave-uniform base + lane*16
#define GL16(g, l) __builtin_amdgcn_global_load_lds( \
    (const __attribute__((address_space(1))) unsigned int*)(g), \
    (__attribute__((address_space(3))) unsigned int*)(l), 16, 0, 0)

// Bank-conflict-free chunk rotation (rule #21): linear LDS dest, permuted
// global source chunk (c - (tid>>3))&3, matching permuted read rotation
// ((lk + (l16>>1))&3). Verified: conflict counter 9.17M -> 0.79M.
//
// Triple-buffer schedule (this round): iteration t stages tile t+2, waits
// vmcnt(2*loads) = own tile-t loads landed (tiles t+1,t+2 in flight ->
// ~2 iterations of latency slack), barrier, computes buf[t%3], barrier.
// Buf b is next overwritten by STAGE(t+3), issued only after iteration t's
// trailing barrier (all waves done reading b) -> race-free.

__device__ __forceinline__ u16 f2b(float v) {
  __bf16 h = (__bf16)v;
  return __builtin_bit_cast(u16, h);
}

// ---- P slice: f32 -> bf16 row-major (P) + bf16 transposed (PT) ----
__global__ void k_convP(const float* __restrict__ P, char* ws, int sliceBase) {
  __shared__ float tile[64][65];
  int s = blockIdx.z;
  const float* Ps = P + (size_t)(sliceBase + s) * NN * NN;
  char* base = ws + SLICE0 + (size_t)s * PS_BYTES;
  u16* Pb  = (u16*)(base + OFF_P);
  u16* PbT = (u16*)(base + OFF_PT);
  int r0 = blockIdx.y * 64, c0 = blockIdx.x * 64;
  int tid = threadIdx.x;
  int tc = tid & 15, tr = tid >> 4;
  for (int rr = 0; rr < 64; rr += 16) {
    int r = rr + tr;
    float4 v = *(const float4*)&Ps[(size_t)(r0 + r) * NN + c0 + tc * 4];
    tile[r][tc * 4 + 0] = v.x;
    tile[r][tc * 4 + 1] = v.y;
    tile[r][tc * 4 + 2] = v.z;
    tile[r][tc * 4 + 3] = v.w;
    u16x4 pk = {f2b(v.x), f2b(v.y), f2b(v.z), f2b(v.w)};
    *(u16x4*)&Pb[(size_t)(r0 + r) * NN + c0 + tc * 4] = pk;
  }
  __syncthreads();
  for (int it = 0; it < 4; ++it) {
    int oc = (tid >> 4) + it * 16;
    int ch = tid & 15;
    u16x4 pk = {f2b(tile[ch * 4 + 0][oc]), f2b(tile[ch * 4 + 1][oc]),
                f2b(tile[ch * 4 + 2][oc]), f2b(tile[ch * 4 + 3][oc])};
    *(u16x4*)&PbT[(size_t)(c0 + oc) * NN + r0 + ch * 4] = pk;
  }
}

// ---- X slice: f32 [1024][64] -> bf16 XT [64][1024] ----
__global__ void k_convX(const float* __restrict__ X, char* ws, int sliceBase) {
  __shared__ float tile[64][65];
  int s = blockIdx.z;
  const float* Xs = X + (size_t)(sliceBase + s) * NN * FF;
  u16* XT = (u16*)(ws + SLICE0 + (size_t)s * PS_BYTES + OFF_XT);
  int r0 = blockIdx.x * 64;
  int tx = threadIdx.x & 63, ty = threadIdx.x >> 6;
  for (int rr = 0; rr < 64; rr += 4)
    tile[rr + ty][tx] = Xs[(size_t)(r0 + rr + ty) * FF + tx];
  __syncthreads();
  for (int rr = 0; rr < 64; rr += 4)
    XT[(size_t)(rr + ty) * NN + r0 + tx] = f2b(tile[tx][rr + ty]);
}

__global__ void k_msum(const float* __restrict__ mask, float* msum) {
  int s = blockIdx.x;
  const float* m = mask + (size_t)s * NN;
  int t = threadIdx.x;
  float v = m[t] + m[t + 256] + m[t + 512] + m[t + 768];
  for (int o = 32; o; o >>= 1) v += __shfl_down(v, o);
  __shared__ float ps[4];
  if ((t & 63) == 0) ps[t >> 6] = v;
  __syncthreads();
  if (t == 0) msum[s] = ps[0] + ps[1] + ps[2] + ps[3];
}

// ---- squaring GEMM: C = A @ B (B given transposed). Writes C bf16 and
// optionally C^T (offT>=0). 128x128 tile, BK=32, 4 waves, global_load_lds,
// XCD swizzle, chunk-rotation LDS, TRIPLE-buffer counted-vmcnt pipeline.
__global__ __launch_bounds__(256)
void k_square(char* ws, int offA, int offB, int offC, int offT) {
  __shared__ u16 sh[24576];  // 48KB: buf b @ b*8192 u16 (A 4096 | B 4096)

  unsigned nwg = gridDim.x, wg = blockIdx.x;
  unsigned newid = (wg & 7) * (nwg >> 3) + (wg >> 3);  // slice-per-XCD
  int z = newid >> 6;
  int by = (newid >> 3) & 7, bx = newid & 7;

  char* base = ws + SLICE0 + (size_t)z * PS_BYTES;
  const u16* A  = (const u16*)(base + offA);
  const u16* Bt = (const u16*)(base + offB);
  u16* C        = (u16*)(base + offC);

  const int tid = threadIdx.x;
  const int lane = tid & 63, wave = tid >> 6;
  const int wr = wave >> 1, wc = wave & 1;
  const int l16 = lane & 15, lk = lane >> 4;
  const int bm = by * 128, bn = bx * 128;

  const int pc = (((tid & 3) - (tid >> 3)) & 3) << 3;
  const u16* gA = A + (size_t)(bm + (tid >> 2)) * NN + pc;
  const u16* gB = Bt + (size_t)(bn + (tid >> 2)) * NN + pc;
  const int rot = ((lk + (l16 >> 1)) & 3) << 3;

  f32x4 acc[4][4] = {};

#define SQ_STAGE(k0, buf)                                   \
  {                                                         \
    u16* dA = sh + (buf)*8192 + wave * 512;                 \
    u16* dB = sh + (buf)*8192 + 4096 + wave * 512;          \
    GL16(gA + (k0), dA);                                    \
    GL16(gA + 64 * NN + (k0), dA + 2048);                   \
    GL16(gB + (k0), dB);                                    \
    GL16(gB + 64 * NN + (k0), dB + 2048);                   \
  }

#define SQ_COMPUTE(buf)                                                      \
  {                                                                          \
    const u16* bA = sh + (buf)*8192;                                         \
    const u16* bB = sh + (buf)*8192 + 4096;                                  \
    bfx8 af[4], bf[4];                                                       \
    _Pragma("unroll") for (int m = 0; m < 4; ++m)                            \
        af[m] = *(const bfx8*)&bA[(wr * 64 + m * 16 + l16) * 32 + rot];      \
    _Pragma("unroll") for (int n = 0; n < 4; ++n)                            \
        bf[n] = *(const bfx8*)&bB[(wc * 64 + n * 16 + l16) * 32 + rot];      \
    __builtin_amdgcn_s_setprio(1);                                           \
    _Pragma("unroll") for (int m = 0; m < 4; ++m)                            \
        _Pragma("unroll") for (int n = 0; n < 4; ++n)                        \
            acc[m][n] = __builtin_amdgcn_mfma_f32_16x16x32_bf16(             \
                af[m], bf[n], acc[m][n], 0, 0, 0);                           \
    __builtin_amdgcn_s_setprio(0);                                           \
  }

#define SQ_STEP(tile, sbuf, cbuf, vm)                          \
  SQ_STAGE((tile) * 32, sbuf);                                 \
  asm volatile("s_waitcnt vmcnt(" #vm ")" ::: "memory");       \
  __builtin_amdgcn_s_barrier();                                \
  SQ_COMPUTE(cbuf);                                            \
  __builtin_amdgcn_s_barrier();

  SQ_STAGE(0, 0);
  SQ_STAGE(32, 1);
  for (int j = 0; j < 10; ++j) {
    int t = 3 * j;
    SQ_STEP(t + 2, 2, 0, 8)
    SQ_STEP(t + 3, 0, 1, 8)
    SQ_STEP(t + 4, 1, 2, 8)
  }
  // t=30 (buf 0): tile 31's 4 loads still outstanding
  asm volatile("s_waitcnt vmcnt(4)" ::: "memory");
  __builtin_amdgcn_s_barrier();
  SQ_COMPUTE(0);
  __builtin_amdgcn_s_barrier();
  // t=31 (buf 1)
  asm volatile("s_waitcnt vmcnt(0)" ::: "memory");
  __builtin_amdgcn_s_barrier();
  SQ_COMPUTE(1);

  // C store (bf16 scalar)
#pragma unroll
  for (int m = 0; m < 4; ++m) {
    int row0 = bm + wr * 64 + m * 16 + lk * 4;
#pragma unroll
    for (int n = 0; n < 4; ++n) {
      int col = bn + wc * 64 + n * 16 + l16;
#pragma unroll
      for (int r = 0; r < 4; ++r)
        C[(size_t)(row0 + r) * NN + col] = f2b(acc[m][n][r]);
    }
  }

  // C^T via per-wave LDS bounce: 4 passes of 16 out-rows, 16B stores
  if (offT >= 0) {
    u16* T = (u16*)(base + offT);
    u16* reg = sh + wave * 1152;  // [16][72] u16, 16B-aligned rows
#pragma unroll
    for (int n = 0; n < 4; ++n) {
      __syncthreads();
#pragma unroll
      for (int m = 0; m < 4; ++m) {
        u16x4 pk = {f2b(acc[m][n][0]), f2b(acc[m][n][1]),
                    f2b(acc[m][n][2]), f2b(acc[m][n][3])};
        *(u16x4*)&reg[l16 * 72 + m * 16 + lk * 4] = pk;
      }
      __syncthreads();
#pragma unroll
      for (int h = 0; h < 2; ++h) {
        int row = (lane >> 3) + 8 * h;
        int c8 = lane & 7;
        uint4 v = *(const uint4*)&reg[row * 72 + c8 * 8];
        *(uint4*)&T[(size_t)(bn + wc * 64 + n * 16 + row) * NN + bm + wr * 64 + c8 * 8] = v;
      }
    }
  }
}

// ---- unified narrow GEMM: [1024x64] = A[1024x1024] @ Bt_sub[64][1024].
// 8 blocks of 128 rows per (slice,sub); 4 waves (2Mx2N), per-wave 64x32.
// Triple-buffer pipeline (3 GL16/tile -> vmcnt 6/3/0). LDS 36KB.
struct NA {
  int a, nsub, rawK;
  int bt0, bt1, bt2;
  int d0, d1, d2;
  int pk0, pk1, pk2;
  int f0, f1, f2;
  int ta0, ta1, ta2;
  int tv0, tv1, tv2;
};

__global__ __launch_bounds__(256)
void k_nar(char* ws, int sliceBase, float* __restrict__ pooled, NA na) {
  __shared__ u16 sh[18432];  // 36KB: buf b @ b*6144 u16 (A 4096 | B 2048)
  unsigned nwg = gridDim.x, wg = blockIdx.x;
  unsigned newid = (wg & 7) * (nwg >> 3) + (wg >> 3);
  int by = newid & 7;
  int rest = newid >> 3;
  int sub = rest % na.nsub;
  int s = rest / na.nsub;
  char* base = ws + SLICE0 + (size_t)s * PS_BYTES;

  int bt  = sub == 0 ? na.bt0 : (sub == 1 ? na.bt1 : na.bt2);
  int dof = sub == 0 ? na.d0  : (sub == 1 ? na.d1  : na.d2);
  int pk  = sub == 0 ? na.pk0 : (sub == 1 ? na.pk1 : na.pk2);
  int fo  = sub == 0 ? na.f0  : (sub == 1 ? na.f1  : na.f2);
  int tao = sub == 0 ? na.ta0 : (sub == 1 ? na.ta1 : na.ta2);
  int tvo = sub == 0 ? na.tv0 : (sub == 1 ? na.tv1 : na.tv2);

  const u16* A  = (const u16*)(base + na.a);
  const u16* Bt = (const u16*)(base + bt);
  int poolBase = (sliceBase + s) * (KFEAT * FF);

  const int tid = threadIdx.x;
  const int lane = tid & 63, wave = tid >> 6;
  const int wr = wave >> 1, wc = wave & 1;
  const int l16 = lane & 15, lk = lane >> 4;
  const int bm = by * 128;

  const int pc = (((tid & 3) - (tid >> 3)) & 3) << 3;
  const u16* gA = A + (size_t)(bm + (tid >> 2)) * NN + pc;
  const u16* gB = Bt + (size_t)(tid >> 2) * NN + pc;
  const int rot = ((lk + (l16 >> 1)) & 3) << 3;

  f32x4 acc[4][2] = {};

#define FT_STAGE(k0, buf)                                   \
  {                                                         \
    u16* dA = sh + (buf)*6144 + wave * 512;                 \
    u16* dB = sh + (buf)*6144 + 4096 + wave * 512;          \
    GL16(gA + (k0), dA);                                    \
    GL16(gA + 64 * NN + (k0), dA + 2048);                   \
    GL16(gB + (k0), dB);                                    \
  }

#define FT_COMPUTE(buf)                                                      \
  {                                                                          \
    const u16* bA = sh + (buf)*6144;                                         \
    const u16* bB = sh + (buf)*6144 + 4096;                                  \
    bfx8 af[4], bfr[2];                                                      \
    _Pragma("unroll") for (int m = 0; m < 4; ++m)                            \
        af[m] = *(const bfx8*)&bA[(wr * 64 + m * 16 + l16) * 32 + rot];      \
    _Pragma("unroll") for (int n = 0; n < 2; ++n)                            \
        bfr[n] = *(const bfx8*)&bB[(wc * 32 + n * 16 + l16) * 32 + rot];     \
    __builtin_amdgcn_s_setprio(1);                                           \
    _Pragma("unroll") for (int m = 0; m < 4; ++m)                            \
        _Pragma("unroll") for (int n = 0; n < 2; ++n)                        \
            acc[m][n] = __builtin_amdgcn_mfma_f32_16x16x32_bf16(             \
                af[m], bfr[n], acc[m][n], 0, 0, 0);                          \
    __builtin_amdgcn_s_setprio(0);                                           \
  }

#define FT_STEP(tile, sbuf, cbuf, vm)                          \
  FT_STAGE((tile) * 32, sbuf);                                 \
  asm volatile("s_waitcnt vmcnt(" #vm ")" ::: "memory");       \
  __builtin_amdgcn_s_barrier();                                \
  FT_COMPUTE(cbuf);                                            \
  __builtin_amdgcn_s_barrier();

  FT_STAGE(0, 0);
  FT_STAGE(32, 1);
  for (int j = 0; j < 10; ++j) {
    int t = 3 * j;
    FT_STEP(t + 2, 2, 0, 6)
    FT_STEP(t + 3, 0, 1, 6)
    FT_STEP(t + 4, 1, 2, 6)
  }
  asm volatile("s_waitcnt vmcnt(3)" ::: "memory");
  __builtin_amdgcn_s_barrier();
  FT_COMPUTE(0);
  __builtin_amdgcn_s_barrier();
  asm volatile("s_waitcnt vmcnt(0)" ::: "memory");
  __builtin_amdgcn_s_barrier();
  FT_COMPUTE(1);

  const float* D = dof >= 0 ? (const float*)(base + dof) : nullptr;
  float* F  = fo  >= 0 ? (float*)(base + fo)  : nullptr;
  u16* Ta   = tao >= 0 ? (u16*)(base + tao)   : nullptr;
  u16* Tv   = tvo >= 0 ? (u16*)(base + tvo)   : nullptr;

  float ps[2] = {0.f, 0.f};
  float pr[2] = {0.f, 0.f};

#pragma unroll
  for (int m = 0; m < 4; ++m) {
    int row0 = bm + wr * 64 + m * 16 + lk * 4;
#pragma unroll
    for (int n = 0; n < 2; ++n) {
      int col = wc * 32 + n * 16 + l16;
      float v0 = acc[m][n][0], v1 = acc[m][n][1], v2 = acc[m][n][2], v3 = acc[m][n][3];
      float w0 = v0, w1 = v1, w2 = v2, w3 = v3;
      if (D) {
        w0 = v0 - D[(size_t)(row0 + 0) * FF + col];
        w1 = v1 - D[(size_t)(row0 + 1) * FF + col];
        w2 = v2 - D[(size_t)(row0 + 2) * FF + col];
        w3 = v3 - D[(size_t)(row0 + 3) * FF + col];
      }
      float a0 = fabsf(w0), a1 = fabsf(w1), a2 = fabsf(w2), a3 = fabsf(w3);
      if (pk >= 0) ps[n] += a0 + a1 + a2 + a3;
      if (na.rawK >= 0) pr[n] += v0 + v1 + v2 + v3;
      if (F) {
        F[(size_t)(row0 + 0) * FF + col] = v0;
        F[(size_t)(row0 + 1) * FF + col] = v1;
        F[(size_t)(row0 + 2) * FF + col] = v2;
        F[(size_t)(row0 + 3) * FF + col] = v3;
      }
      if (Ta) {
        u16x4 pkk = {f2b(a0), f2b(a1), f2b(a2), f2b(a3)};
        *(u16x4*)&Ta[(size_t)col * NN + row0] = pkk;
      }
      if (Tv) {
        u16x4 pkk = {f2b(v0), f2b(v1), f2b(v2), f2b(v3)};
        *(u16x4*)&Tv[(size_t)col * NN + row0] = pkk;
      }
    }
  }

  if (pk >= 0) {
#pragma unroll
    for (int n = 0; n < 2; ++n) {
      float v = ps[n];
      v += __shfl_xor(v, 16);
      v += __shfl_xor(v, 32);
      if (lane < 16)
        atomicAdd(&pooled[poolBase + pk * FF + wc * 32 + n * 16 + lane], v);
    }
  }
  if (na.rawK >= 0) {
#pragma unroll
    for (int n = 0; n < 2; ++n) {
      float v = pr[n];
      v += __shfl_xor(v, 16);
      v += __shfl_xor(v, 32);
      if (lane < 16)
        atomicAdd(&pooled[poolBase + na.rawK * FF + wc * 32 + n * 16 + lane], v);
    }
  }
}

__global__ void k_final(const float* __restrict__ pooled, const float* __restrict__ msum,
                        float* __restrict__ out, int total) {
  int i = blockIdx.x * 256 + threadIdx.x;
  if (i < total) out[i] = pooled[i] / msum[i / (KFEAT * FF)];
}

static inline NA mkNA(int a, int nsub, int rawK,
                      int bt0, int bt1, int bt2, int d0, int d1, int d2,
                      int pk0, int pk1, int pk2, int f0, int f1, int f2,
                      int ta0, int ta1, int ta2, int tv0, int tv1, int tv2) {
  NA x;
  x.a = a; x.nsub = nsub; x.rawK = rawK;
  x.bt0 = bt0; x.bt1 = bt1; x.bt2 = bt2;
  x.d0 = d0; x.d1 = d1; x.d2 = d2;
  x.pk0 = pk0; x.pk1 = pk1; x.pk2 = pk2;
  x.f0 = f0; x.f1 = f1; x.f2 = f2;
  x.ta0 = ta0; x.ta1 = ta1; x.ta2 = ta2;
  x.tv0 = tv0; x.tv1 = tv1; x.tv2 = tv2;
  return x;
}

extern "C" void kernel_launch(void* const* d_in, const int* in_sizes, int n_in,
                              void* d_out, int out_size, void* d_ws, size_t ws_size,
                              hipStream_t stream) {
  const float* P = (const float*)d_in[0];
  const float* X = (const float*)d_in[1];
  const float* mask = (const float*)d_in[2];
  float* out = (float*)d_out;
  char* ws = (char*)d_ws;
  float* pooled = (float*)ws;
  float* msum = (float*)(ws + MSUM_OFF);

  hipMemsetAsync(pooled, 0, POOL_BYTES, stream);
  k_msum<<<NSLICE, 256, 0, stream>>>(mask, msum);

  int S = 1;
  if (ws_size > SLICE0 + PS_BYTES) S = (int)((ws_size - SLICE0) / PS_BYTES);
  if (S > NSLICE) S = NSLICE;
  if (S < 1) S = 1;

  for (int b0 = 0; b0 < NSLICE; b0 += S) {
    int n = (NSLICE - b0 < S) ? (NSLICE - b0) : S;
    k_convP<<<dim3(16, 16, n), 256, 0, stream>>>(P, ws, b0);
    k_convX<<<dim3(16, 1, n), 256, 0, stream>>>(X, ws, b0);
    // P2 = P@P (+P2^T), P4 = P2@P2
    k_square<<<64 * n, 256, 0, stream>>>(ws, OFF_P, OFF_PT, OFF_P2, (int)OFF_P2T);
    k_square<<<64 * n, 256, 0, stream>>>(ws, OFF_P2, OFF_P2T, OFF_P4, -1);
    // Y1 = P X
    NA a1 = mkNA(OFF_P, 1, -1, OFF_XT, -1, -1, -1, -1, -1, -1, -1, -1,
                 OFF_Y1, -1, -1, -1, -1, -1, -1, -1, -1);
    k_nar<<<8 * n, 256, 0, stream>>>(ws, b0, pooled, a1);
    // Y2 = P2 X ; s0 = |Y2-Y1| pool k=1
    NA a2 = mkNA(OFF_P2, 1, -1, OFF_XT, -1, -1, (int)OFF_Y1, -1, -1, 1, -1, -1,
                 OFF_Y2, -1, -1, -1, -1, -1, -1, -1, -1);
    k_nar<<<8 * n, 256, 0, stream>>>(ws, b0, pooled, a2);
    // Y4 = P4 X ; s1 = |Y4-Y2| pool k=2, s1T ; Y4 f32 + Y4T
    NA a3 = mkNA(OFF_P4, 1, -1, OFF_XT, -1, -1, (int)OFF_Y2, -1, -1, 2, -1, -1,
                 OFF_Y4, -1, -1, OFF_S1T, -1, -1, OFF_Y4T, -1, -1);
    k_nar<<<8 * n, 256, 0, stream>>>(ws, b0, pooled, a3);
    // Y8 = P4 Y4 ; s2 = |Y8-Y4| pool k=3, s2T ; Y8 f32 + Y8T
    NA a4 = mkNA(OFF_P4, 1, -1, OFF_Y4T, -1, -1, (int)OFF_Y4, -1, -1, 3, -1, -1,
                 OFF_Y8, -1, -1, OFF_S2T, -1, -1, OFF_Y8T, -1, -1);
    k_nar<<<8 * n, 256, 0, stream>>>(ws, b0, pooled, a4);
    // Y12 = P4 Y8 -> Y12T
    NA a5 = mkNA(OFF_P4, 1, -1, OFF_Y8T, -1, -1, -1, -1, -1, -1, -1, -1,
                 -1, -1, -1, -1, -1, -1, OFF_Y12T, -1, -1);
    k_nar<<<8 * n, 256, 0, stream>>>(ws, b0, pooled, a5);
    // Y16 = P4 Y12 ; s3 = |Y16-Y8| pool k=4, s3T ; F0 raw pool k=0
    NA a6 = mkNA(OFF_P4, 1, 0, OFF_Y12T, -1, -1, (int)OFF_Y8, -1, -1, 4, -1, -1,
                 -1, -1, -1, OFF_S3T, -1, -1, -1, -1, -1);
    k_nar<<<8 * n, 256, 0, stream>>>(ws, b0, pooled, a6);
    // P*{s1,s2,s3} -> f32
    NA a7 = mkNA(OFF_P, 3, -1, OFF_S1T, OFF_S2T, OFF_S3T, -1, -1, -1,
                 -1, -1, -1, OFF_PS1, OFF_PS2, OFF_PS3,
                 -1, -1, -1, -1, -1, -1);
    k_nar<<<24 * n, 256, 0, stream>>>(ws, b0, pooled, a7);
    // P2*{s1,s2,s3} ; |psi0 s_i| pools k=5,6,8 ; keep f32 for psi1
    NA a8 = mkNA(OFF_P2, 3, -1, OFF_S1T, OFF_S2T, OFF_S3T,
                 (int)OFF_PS1, (int)OFF_PS2, (int)OFF_PS3, 5, 6, 8,
                 OFF_QS1, OFF_QS2, OFF_QS3, -1, -1, -1, -1, -1, -1);
    k_nar<<<24 * n, 256, 0, stream>>>(ws, b0, pooled, a8);
    // P4*{s2,s3} ; |psi1 s_i| pools k=7,9 ; W = P4 s3 (f32 + WT)
    NA a9 = mkNA(OFF_P4, 2, -1, OFF_S2T, OFF_S3T, -1,
                 (int)OFF_QS2, (int)OFF_QS3, -1, 7, 9, -1,
                 -1, OFF_W, -1, -1, -1, -1, -1, OFF_WT, -1);
    k_nar<<<16 * n, 256, 0, stream>>>(ws, b0, pooled, a9);
    // P4*W ; |psi2 s3| pool k=10
    NA a10 = mkNA(OFF_P4, 1, -1, OFF_WT, -1, -1, (int)OFF_W, -1, -1, 10, -1, -1,
                  -1, -1, -1, -1, -1, -1, -1, -1, -1);
    k_nar<<<8 * n, 256, 0, stream>>>(ws, b0, pooled, a10);
  }
  int total = NSLICE * KFEAT * FF;
  k_final<<<(total + 255) / 256, 256, 0, stream>>>(pooled, msum, out, total);
}

// Round 9
// 466.299 us; speedup vs baseline: 1.0463x; 1.0315x over previous
//
#include <hip/hip_runtime.h>

typedef unsigned short u16;
typedef __bf16 bfx8 __attribute__((ext_vector_type(8)));
typedef float f32x4 __attribute__((ext_vector_type(4)));
typedef unsigned short u16x4 __attribute__((ext_vector_type(4)));

#define NN 1024
#define FF 64
#define NSLICE 32
#define KFEAT 11

// ---- workspace layout ----
#define POOL_BYTES (NSLICE * KFEAT * FF * 4)  // 90112
#define MSUM_OFF   POOL_BYTES
#define SLICE0     ((size_t)1 << 20)
#define MB1        (1024u * 1024u)
#define KB128      (131072u)
#define KB256      (262144u)
// bf16 NxN matrices
#define OFF_P    0u
#define OFF_PT   (2u * MB1)
#define OFF_P2   (4u * MB1)
#define OFF_P2T  (6u * MB1)
#define OFF_P4   (8u * MB1)
// bf16 [64][1024] transposed narrow operands
#define OFF_XT   (10u * MB1)
#define OFF_Y4T  (10u * MB1 + 1u * KB128)
#define OFF_Y8T  (10u * MB1 + 2u * KB128)
#define OFF_Y12T (10u * MB1 + 3u * KB128)
#define OFF_S1T  (10u * MB1 + 4u * KB128)
#define OFF_S2T  (10u * MB1 + 5u * KB128)
#define OFF_S3T  (10u * MB1 + 6u * KB128)
#define OFF_WT   (10u * MB1 + 7u * KB128)
// f32 [1024][64] narrow results
#define OFF_Y1   (11u * MB1)
#define OFF_Y2   (11u * MB1 + 1u * KB256)
#define OFF_Y4   (11u * MB1 + 2u * KB256)
#define OFF_Y8   (11u * MB1 + 3u * KB256)
#define OFF_PS1  (11u * MB1 + 4u * KB256)
#define OFF_PS2  (11u * MB1 + 5u * KB256)
#define OFF_PS3  (11u * MB1 + 6u * KB256)
#define OFF_QS2  (11u * MB1 + 7u * KB256)
#define OFF_QS3  (11u * MB1 + 8u * KB256)
#define OFF_W    (11u * MB1 + 9u * KB256)
#define PS_BYTES ((size_t)(14u * MB1))

// async global->LDS, 16B per lane; LDS dest = wave-uniform base + lane*16
#define GL16(g, l) __builtin_amdgcn_global_load_lds( \
    (const __attribute__((address_space(1))) unsigned int*)(g), \
    (__attribute__((address_space(3))) unsigned int*)(l), 16, 0, 0)

// Bank-conflict-free chunk rotation (rule #21): linear LDS dest, permuted
// global source chunk (c - (tid>>3))&3, matching permuted read rotation
// ((lk + (l16>>1))&3). Verified: conflict counter 9.17M -> 0.79M.

__device__ __forceinline__ u16 f2b(float v) {
  __bf16 h = (__bf16)v;
  return __builtin_bit_cast(u16, h);
}

// ---- P slice: f32 -> bf16 row-major (P) + bf16 transposed (PT) ----
__global__ void k_convP(const float* __restrict__ P, char* ws, int sliceBase) {
  __shared__ float tile[64][65];
  int s = blockIdx.z;
  const float* Ps = P + (size_t)(sliceBase + s) * NN * NN;
  char* base = ws + SLICE0 + (size_t)s * PS_BYTES;
  u16* Pb  = (u16*)(base + OFF_P);
  u16* PbT = (u16*)(base + OFF_PT);
  int r0 = blockIdx.y * 64, c0 = blockIdx.x * 64;
  int tid = threadIdx.x;
  int tc = tid & 15, tr = tid >> 4;
  for (int rr = 0; rr < 64; rr += 16) {
    int r = rr + tr;
    float4 v = *(const float4*)&Ps[(size_t)(r0 + r) * NN + c0 + tc * 4];
    tile[r][tc * 4 + 0] = v.x;
    tile[r][tc * 4 + 1] = v.y;
    tile[r][tc * 4 + 2] = v.z;
    tile[r][tc * 4 + 3] = v.w;
    u16x4 pk = {f2b(v.x), f2b(v.y), f2b(v.z), f2b(v.w)};
    *(u16x4*)&Pb[(size_t)(r0 + r) * NN + c0 + tc * 4] = pk;
  }
  __syncthreads();
  for (int it = 0; it < 4; ++it) {
    int oc = (tid >> 4) + it * 16;
    int ch = tid & 15;
    u16x4 pk = {f2b(tile[ch * 4 + 0][oc]), f2b(tile[ch * 4 + 1][oc]),
                f2b(tile[ch * 4 + 2][oc]), f2b(tile[ch * 4 + 3][oc])};
    *(u16x4*)&PbT[(size_t)(c0 + oc) * NN + r0 + ch * 4] = pk;
  }
}

// ---- X slice: f32 [1024][64] -> bf16 XT [64][1024] ----
__global__ void k_convX(const float* __restrict__ X, char* ws, int sliceBase) {
  __shared__ float tile[64][65];
  int s = blockIdx.z;
  const float* Xs = X + (size_t)(sliceBase + s) * NN * FF;
  u16* XT = (u16*)(ws + SLICE0 + (size_t)s * PS_BYTES + OFF_XT);
  int r0 = blockIdx.x * 64;
  int tx = threadIdx.x & 63, ty = threadIdx.x >> 6;
  for (int rr = 0; rr < 64; rr += 4)
    tile[rr + ty][tx] = Xs[(size_t)(r0 + rr + ty) * FF + tx];
  __syncthreads();
  for (int rr = 0; rr < 64; rr += 4)
    XT[(size_t)(rr + ty) * NN + r0 + tx] = f2b(tile[tx][rr + ty]);
}

__global__ void k_msum(const float* __restrict__ mask, float* msum) {
  int s = blockIdx.x;
  const float* m = mask + (size_t)s * NN;
  int t = threadIdx.x;
  float v = m[t] + m[t + 256] + m[t + 512] + m[t + 768];
  for (int o = 32; o; o >>= 1) v += __shfl_down(v, o);
  __shared__ float ps[4];
  if ((t & 63) == 0) ps[t >> 6] = v;
  __syncthreads();
  if (t == 0) msum[s] = ps[0] + ps[1] + ps[2] + ps[3];
}

// ---- squaring GEMM (r6-exact schedule: dbuf, vmcnt(4), 32KB LDS) ----
__global__ __launch_bounds__(256)
void k_square(char* ws, int offA, int offB, int offC, int offT) {
  __shared__ u16 sh[16384];  // 32KB: A bufs @0/4096, B bufs @8192/12288

  unsigned nwg = gridDim.x, wg = blockIdx.x;
  unsigned newid = (wg & 7) * (nwg >> 3) + (wg >> 3);  // slice-per-XCD
  int z = newid >> 6;
  int by = (newid >> 3) & 7, bx = newid & 7;

  char* base = ws + SLICE0 + (size_t)z * PS_BYTES;
  const u16* A  = (const u16*)(base + offA);
  const u16* Bt = (const u16*)(base + offB);
  u16* C        = (u16*)(base + offC);

  const int tid = threadIdx.x;
  const int lane = tid & 63, wave = tid >> 6;
  const int wr = wave >> 1, wc = wave & 1;
  const int l16 = lane & 15, lk = lane >> 4;
  const int bm = by * 128, bn = bx * 128;

  const int pc = (((tid & 3) - (tid >> 3)) & 3) << 3;
  const u16* gA = A + (size_t)(bm + (tid >> 2)) * NN + pc;
  const u16* gB = Bt + (size_t)(bn + (tid >> 2)) * NN + pc;
  const int rot = ((lk + (l16 >> 1)) & 3) << 3;

  f32x4 acc[4][4] = {};

#define SQ_STAGE(k0, buf)                                   \
  {                                                         \
    u16* dA = sh + (buf)*4096 + wave * 512;                 \
    u16* dB = sh + 8192 + (buf)*4096 + wave * 512;          \
    GL16(gA + (k0), dA);                                    \
    GL16(gA + 64 * NN + (k0), dA + 2048);                   \
    GL16(gB + (k0), dB);                                    \
    GL16(gB + 64 * NN + (k0), dB + 2048);                   \
  }

#define SQ_COMPUTE(buf)                                                      \
  {                                                                          \
    const u16* bA = sh + (buf)*4096;                                         \
    const u16* bB = sh + 8192 + (buf)*4096;                                  \
    bfx8 af[4], bf[4];                                                       \
    _Pragma("unroll") for (int m = 0; m < 4; ++m)                            \
        af[m] = *(const bfx8*)&bA[(wr * 64 + m * 16 + l16) * 32 + rot];      \
    _Pragma("unroll") for (int n = 0; n < 4; ++n)                            \
        bf[n] = *(const bfx8*)&bB[(wc * 64 + n * 16 + l16) * 32 + rot];      \
    __builtin_amdgcn_s_setprio(1);                                           \
    _Pragma("unroll") for (int m = 0; m < 4; ++m)                            \
        _Pragma("unroll") for (int n = 0; n < 4; ++n)                        \
            acc[m][n] = __builtin_amdgcn_mfma_f32_16x16x32_bf16(             \
                af[m], bf[n], acc[m][n], 0, 0, 0);                           \
    __builtin_amdgcn_s_setprio(0);                                           \
  }

  SQ_STAGE(0, 0);
#pragma unroll 2
  for (int t = 1; t < 32; ++t) {
    SQ_STAGE(t * 32, t & 1);
    asm volatile("s_waitcnt vmcnt(4)" ::: "memory");  // own tile t-1 done
    __builtin_amdgcn_s_barrier();                     // -> globally done
    SQ_COMPUTE((t - 1) & 1);
    __builtin_amdgcn_s_barrier();                     // reads done
  }
  asm volatile("s_waitcnt vmcnt(0)" ::: "memory");
  __builtin_amdgcn_s_barrier();
  SQ_COMPUTE(1);

  // C store (bf16 scalar)
#pragma unroll
  for (int m = 0; m < 4; ++m) {
    int row0 = bm + wr * 64 + m * 16 + lk * 4;
#pragma unroll
    for (int n = 0; n < 4; ++n) {
      int col = bn + wc * 64 + n * 16 + l16;
#pragma unroll
      for (int r = 0; r < 4; ++r)
        C[(size_t)(row0 + r) * NN + col] = f2b(acc[m][n][r]);
    }
  }

  // C^T via per-wave LDS bounce: 4 passes of 16 out-rows, 16B stores
  if (offT >= 0) {
    u16* T = (u16*)(base + offT);
    u16* reg = sh + wave * 1152;  // [16][72] u16, 16B-aligned rows
#pragma unroll
    for (int n = 0; n < 4; ++n) {
      __syncthreads();
#pragma unroll
      for (int m = 0; m < 4; ++m) {
        u16x4 pk = {f2b(acc[m][n][0]), f2b(acc[m][n][1]),
                    f2b(acc[m][n][2]), f2b(acc[m][n][3])};
        *(u16x4*)&reg[l16 * 72 + m * 16 + lk * 4] = pk;
      }
      __syncthreads();
#pragma unroll
      for (int h = 0; h < 2; ++h) {
        int row = (lane >> 3) + 8 * h;
        int c8 = lane & 7;
        uint4 v = *(const uint4*)&reg[row * 72 + c8 * 8];
        *(uint4*)&T[(size_t)(bn + wc * 64 + n * 16 + row) * NN + bm + wr * 64 + c8 * 8] = v;
      }
    }
  }
}

// ---- fused narrow GEMM: for one A[1024x1024], NB B-operands (Bt [64][1024])
// share the A staging: acc_j = A @ B_j. 64-row M-tiles (16 blocks/slice),
// 4 waves (2Mx2N), per-wave 32x32 per operand. Per-slot epilogue flags:
// d = f32 diff source, pk = pool-|w| feature idx, f = f32 out, ta = bf16-T
// of |w|, tv = bf16-T of v. rawK pools raw v of slot 0 (F0).
struct NA {
  int a, rawK;
  int bt[3], d[3], pk[3], f[3], ta[3], tv[3];
};

template <int NB>
__global__ __launch_bounds__(256)
void k_nar(char* ws, int sliceBase, float* __restrict__ pooled, NA na) {
  __shared__ u16 sh[16384];  // 32KB: buf b @ b*8192: A[2048] | B_j[2048]*3
  unsigned nwg = gridDim.x, wg = blockIdx.x;
  unsigned newid = (wg & 7) * (nwg >> 3) + (wg >> 3);  // slice-per-XCD
  int by = newid & 15;
  int s = newid >> 4;
  char* base = ws + SLICE0 + (size_t)s * PS_BYTES;

  const u16* A = (const u16*)(base + na.a);
  int poolBase = (sliceBase + s) * (KFEAT * FF);

  const int tid = threadIdx.x;
  const int lane = tid & 63, wave = tid >> 6;
  const int wr = wave >> 1, wc = wave & 1;
  const int l16 = lane & 15, lk = lane >> 4;
  const int bm = by * 64;

  const int pc = (((tid & 3) - (tid >> 3)) & 3) << 3;
  const u16* gA = A + (size_t)(bm + (tid >> 2)) * NN + pc;
  const u16* gB[NB];
#pragma unroll
  for (int j = 0; j < NB; ++j)
    gB[j] = (const u16*)(base + na.bt[j]) + (size_t)(tid >> 2) * NN + pc;
  const int rot = ((lk + (l16 >> 1)) & 3) << 3;

  f32x4 acc[NB][2][2] = {};

  auto STAGE = [&](int k0, int buf) {
    u16* dA = sh + buf * 8192 + wave * 512;
    GL16(gA + k0, dA);
#pragma unroll
    for (int j = 0; j < NB; ++j) {
      u16* dB = sh + buf * 8192 + 2048 + j * 2048 + wave * 512;
      GL16(gB[j] + k0, dB);
    }
  };
  auto COMPUTE = [&](int buf) {
    const u16* bA = sh + buf * 8192;
    bfx8 af[2];
#pragma unroll
    for (int m = 0; m < 2; ++m)
      af[m] = *(const bfx8*)&bA[(wr * 32 + m * 16 + l16) * 32 + rot];
    __builtin_amdgcn_s_setprio(1);
#pragma unroll
    for (int j = 0; j < NB; ++j) {
      const u16* bB = sh + buf * 8192 + 2048 + j * 2048;
      bfx8 bf[2];
#pragma unroll
      for (int n = 0; n < 2; ++n)
        bf[n] = *(const bfx8*)&bB[(wc * 32 + n * 16 + l16) * 32 + rot];
#pragma unroll
      for (int m = 0; m < 2; ++m)
#pragma unroll
        for (int n = 0; n < 2; ++n)
          acc[j][m][n] = __builtin_amdgcn_mfma_f32_16x16x32_bf16(
              af[m], bf[n], acc[j][m][n], 0, 0, 0);
    }
    __builtin_amdgcn_s_setprio(0);
  };

  STAGE(0, 0);
#pragma unroll 2
  for (int t = 1; t < 32; ++t) {
    STAGE(t * 32, t & 1);
    if constexpr (NB == 1)
      asm volatile("s_waitcnt vmcnt(2)" ::: "memory");
    else if constexpr (NB == 2)
      asm volatile("s_waitcnt vmcnt(3)" ::: "memory");
    else
      asm volatile("s_waitcnt vmcnt(4)" ::: "memory");
    __builtin_amdgcn_s_barrier();
    COMPUTE((t - 1) & 1);
    __builtin_amdgcn_s_barrier();
  }
  asm volatile("s_waitcnt vmcnt(0)" ::: "memory");
  __builtin_amdgcn_s_barrier();
  COMPUTE(1);

#pragma unroll
  for (int j = 0; j < NB; ++j) {
    const float* D = na.d[j] >= 0 ? (const float*)(base + na.d[j]) : nullptr;
    float* F  = na.f[j]  >= 0 ? (float*)(base + na.f[j])  : nullptr;
    u16* Ta   = na.ta[j] >= 0 ? (u16*)(base + na.ta[j])   : nullptr;
    u16* Tv   = na.tv[j] >= 0 ? (u16*)(base + na.tv[j])   : nullptr;
    bool doRaw = (j == 0) && (na.rawK >= 0);

    float ps[2] = {0.f, 0.f};
    float pr[2] = {0.f, 0.f};

#pragma unroll
    for (int m = 0; m < 2; ++m) {
      int row0 = bm + wr * 32 + m * 16 + lk * 4;
#pragma unroll
      for (int n = 0; n < 2; ++n) {
        int col = wc * 32 + n * 16 + l16;
        float v0 = acc[j][m][n][0], v1 = acc[j][m][n][1];
        float v2 = acc[j][m][n][2], v3 = acc[j][m][n][3];
        float w0 = v0, w1 = v1, w2 = v2, w3 = v3;
        if (D) {
          w0 = v0 - D[(size_t)(row0 + 0) * FF + col];
          w1 = v1 - D[(size_t)(row0 + 1) * FF + col];
          w2 = v2 - D[(size_t)(row0 + 2) * FF + col];
          w3 = v3 - D[(size_t)(row0 + 3) * FF + col];
        }
        float a0 = fabsf(w0), a1 = fabsf(w1), a2 = fabsf(w2), a3 = fabsf(w3);
        if (na.pk[j] >= 0) ps[n] += a0 + a1 + a2 + a3;
        if (doRaw) pr[n] += v0 + v1 + v2 + v3;
        if (F) {
          F[(size_t)(row0 + 0) * FF + col] = v0;
          F[(size_t)(row0 + 1) * FF + col] = v1;
          F[(size_t)(row0 + 2) * FF + col] = v2;
          F[(size_t)(row0 + 3) * FF + col] = v3;
        }
        if (Ta) {
          u16x4 pkk = {f2b(a0), f2b(a1), f2b(a2), f2b(a3)};
          *(u16x4*)&Ta[(size_t)col * NN + row0] = pkk;
        }
        if (Tv) {
          u16x4 pkk = {f2b(v0), f2b(v1), f2b(v2), f2b(v3)};
          *(u16x4*)&Tv[(size_t)col * NN + row0] = pkk;
        }
      }
    }

    if (na.pk[j] >= 0) {
#pragma unroll
      for (int n = 0; n < 2; ++n) {
        float v = ps[n];
        v += __shfl_xor(v, 16);
        v += __shfl_xor(v, 32);
        if (lane < 16)
          atomicAdd(&pooled[poolBase + na.pk[j] * FF + wc * 32 + n * 16 + lane], v);
      }
    }
    if (doRaw) {
#pragma unroll
      for (int n = 0; n < 2; ++n) {
        float v = pr[n];
        v += __shfl_xor(v, 16);
        v += __shfl_xor(v, 32);
        if (lane < 16)
          atomicAdd(&pooled[poolBase + na.rawK * FF + wc * 32 + n * 16 + lane], v);
      }
    }
  }
}

__global__ void k_final(const float* __restrict__ pooled, const float* __restrict__ msum,
                        float* __restrict__ out, int total) {
  int i = blockIdx.x * 256 + threadIdx.x;
  if (i < total) out[i] = pooled[i] / msum[i / (KFEAT * FF)];
}

// helper: one-slot NA
static NA mk1(int a, int rawK, int bt, int d, int pk, int f, int ta, int tv) {
  NA x;
  x.a = a; x.rawK = rawK;
  for (int j = 0; j < 3; ++j) {
    x.bt[j] = -1; x.d[j] = -1; x.pk[j] = -1;
    x.f[j] = -1; x.ta[j] = -1; x.tv[j] = -1;
  }
  x.bt[0] = bt; x.d[0] = d; x.pk[0] = pk; x.f[0] = f; x.ta[0] = ta; x.tv[0] = tv;
  return x;
}
static void setslot(NA& x, int j, int bt, int d, int pk, int f, int ta, int tv) {
  x.bt[j] = bt; x.d[j] = d; x.pk[j] = pk; x.f[j] = f; x.ta[j] = ta; x.tv[j] = tv;
}

extern "C" void kernel_launch(void* const* d_in, const int* in_sizes, int n_in,
                              void* d_out, int out_size, void* d_ws, size_t ws_size,
                              hipStream_t stream) {
  const float* P = (const float*)d_in[0];
  const float* X = (const float*)d_in[1];
  const float* mask = (const float*)d_in[2];
  float* out = (float*)d_out;
  char* ws = (char*)d_ws;
  float* pooled = (float*)ws;
  float* msum = (float*)(ws + MSUM_OFF);

  hipMemsetAsync(pooled, 0, POOL_BYTES, stream);
  k_msum<<<NSLICE, 256, 0, stream>>>(mask, msum);

  int S = 1;
  if (ws_size > SLICE0 + PS_BYTES) S = (int)((ws_size - SLICE0) / PS_BYTES);
  if (S > NSLICE) S = NSLICE;
  if (S < 1) S = 1;

  for (int b0 = 0; b0 < NSLICE; b0 += S) {
    int n = (NSLICE - b0 < S) ? (NSLICE - b0) : S;
    k_convP<<<dim3(16, 16, n), 256, 0, stream>>>(P, ws, b0);
    k_convX<<<dim3(16, 1, n), 256, 0, stream>>>(X, ws, b0);
    // P2 = P@P (+P2^T), P4 = P2@P2
    k_square<<<64 * n, 256, 0, stream>>>(ws, OFF_P, OFF_PT, OFF_P2, (int)OFF_P2T);
    k_square<<<64 * n, 256, 0, stream>>>(ws, OFF_P2, OFF_P2T, OFF_P4, -1);

    // n1: Y1 = P X
    NA a1 = mk1(OFF_P, -1, OFF_XT, -1, -1, OFF_Y1, -1, -1);
    k_nar<1><<<16 * n, 256, 0, stream>>>(ws, b0, pooled, a1);
    // n2: Y2 = P2 X ; s0=|Y2-Y1| pool1
    NA a2 = mk1(OFF_P2, -1, OFF_XT, (int)OFF_Y1, 1, OFF_Y2, -1, -1);
    k_nar<1><<<16 * n, 256, 0, stream>>>(ws, b0, pooled, a2);
    // n3: Y4 = P4 X ; s1=|Y4-Y2| pool2 + S1T ; Y4 f32 + Y4T
    NA a3 = mk1(OFF_P4, -1, OFF_XT, (int)OFF_Y2, 2, OFF_Y4, OFF_S1T, OFF_Y4T);
    k_nar<1><<<16 * n, 256, 0, stream>>>(ws, b0, pooled, a3);
    // n4: Y8 = P4 Y4 ; s2 pool3 + S2T ; Y8 f32 + Y8T
    NA a4 = mk1(OFF_P4, -1, OFF_Y4T, (int)OFF_Y4, 3, OFF_Y8, OFF_S2T, OFF_Y8T);
    k_nar<1><<<16 * n, 256, 0, stream>>>(ws, b0, pooled, a4);
    // n5: Y12 = P4 Y8 -> Y12T
    NA a5 = mk1(OFF_P4, -1, OFF_Y8T, -1, -1, -1, -1, OFF_Y12T);
    k_nar<1><<<16 * n, 256, 0, stream>>>(ws, b0, pooled, a5);
    // n6: Y16 = P4 Y12 ; s3=|Y16-Y8| pool4 + S3T ; F0 raw pool0
    NA a6 = mk1(OFF_P4, 0, OFF_Y12T, (int)OFF_Y8, 4, -1, OFF_S3T, -1);
    k_nar<1><<<16 * n, 256, 0, stream>>>(ws, b0, pooled, a6);
    // n7 (fused): P * {s1,s2,s3} -> PS1,PS2,PS3 (one A read)
    NA a7 = mk1(OFF_P, -1, OFF_S1T, -1, -1, OFF_PS1, -1, -1);
    setslot(a7, 1, OFF_S2T, -1, -1, OFF_PS2, -1, -1);
    setslot(a7, 2, OFF_S3T, -1, -1, OFF_PS3, -1, -1);
    k_nar<3><<<16 * n, 256, 0, stream>>>(ws, b0, pooled, a7);
    // n8 (fused): P2 * {s1,s2,s3} ; |psi0 s_i| pools 5,6,8 ; QS2,QS3 f32
    NA a8 = mk1(OFF_P2, -1, OFF_S1T, (int)OFF_PS1, 5, -1, -1, -1);
    setslot(a8, 1, OFF_S2T, (int)OFF_PS2, 6, OFF_QS2, -1, -1);
    setslot(a8, 2, OFF_S3T, (int)OFF_PS3, 8, OFF_QS3, -1, -1);
    k_nar<3><<<16 * n, 256, 0, stream>>>(ws, b0, pooled, a8);
    // n9 (fused): P4 * {s2,s3} ; |psi1 s_i| pools 7,9 ; W = P4 s3 + WT
    NA a9 = mk1(OFF_P4, -1, OFF_S2T, (int)OFF_QS2, 7, -1, -1, -1);
    setslot(a9, 1, OFF_S3T, (int)OFF_QS3, 9, OFF_W, -1, OFF_WT);
    k_nar<2><<<16 * n, 256, 0, stream>>>(ws, b0, pooled, a9);
    // n10: P4 * W ; |psi2 s3| pool 10
    NA a10 = mk1(OFF_P4, -1, OFF_WT, (int)OFF_W, 10, -1, -1, -1);
    k_nar<1><<<16 * n, 256, 0, stream>>>(ws, b0, pooled, a10);
  }
  int total = NSLICE * KFEAT * FF;
  k_final<<<(total + 255) / 256, 256, 0, stream>>>(pooled, msum, out, total);
}

// Round 10
// 392.000 us; speedup vs baseline: 1.2447x; 1.1895x over previous
//
#include <hip/hip_runtime.h>

typedef unsigned short u16;
typedef __bf16 bfx8 __attribute__((ext_vector_type(8)));
typedef float f32x4 __attribute__((ext_vector_type(4)));
typedef unsigned short u16x4 __attribute__((ext_vector_type(4)));

#define NN 1024
#define FF 64
#define NSLICE 32
#define KFEAT 11

// ---- workspace layout ----
#define POOL_BYTES (NSLICE * KFEAT * FF * 4)  // 90112
#define MSUM_OFF   POOL_BYTES
#define SLICE0     ((size_t)1 << 20)
#define MB1        (1024u * 1024u)
#define KB128      (131072u)
#define KB256      (262144u)
// bf16 NxN matrices
#define OFF_P    0u
#define OFF_PT   (2u * MB1)
#define OFF_P2   (4u * MB1)
// bf16 [64][1024] transposed narrow operands (15 x 128KB @ 6MB)
#define OFF_XT   (6u * MB1)
#define OFF_Y2T  (6u * MB1 + 1u * KB128)
#define OFF_Y4T  (6u * MB1 + 2u * KB128)
#define OFF_Y6T  (6u * MB1 + 3u * KB128)
#define OFF_Y8T  (6u * MB1 + 4u * KB128)
#define OFF_Y10T (6u * MB1 + 5u * KB128)
#define OFF_Y12T (6u * MB1 + 6u * KB128)
#define OFF_Y14T (6u * MB1 + 7u * KB128)
#define OFF_S1T  (6u * MB1 + 8u * KB128)
#define OFF_S2T  (6u * MB1 + 9u * KB128)
#define OFF_S3T  (6u * MB1 + 10u * KB128)
#define OFF_TQ2  (6u * MB1 + 11u * KB128)
#define OFF_TQ3  (6u * MB1 + 12u * KB128)
#define OFF_TW4  (6u * MB1 + 13u * KB128)
#define OFF_TP6  (6u * MB1 + 14u * KB128)
// f32 [1024][64] narrow results (10 x 256KB @ 8MB)
#define OFF_Y1   (8u * MB1)
#define OFF_Y2   (8u * MB1 + 1u * KB256)
#define OFF_Y4   (8u * MB1 + 2u * KB256)
#define OFF_Y8   (8u * MB1 + 3u * KB256)
#define OFF_PS1  (8u * MB1 + 4u * KB256)
#define OFF_PS2  (8u * MB1 + 5u * KB256)
#define OFF_PS3  (8u * MB1 + 6u * KB256)
#define OFF_QS2  (8u * MB1 + 7u * KB256)
#define OFF_QS3  (8u * MB1 + 8u * KB256)
#define OFF_W4   (8u * MB1 + 9u * KB256)
#define PS_BYTES ((size_t)(11u * MB1))

// async global->LDS, 16B per lane; LDS dest = wave-uniform base + lane*16
#define GL16(g, l) __builtin_amdgcn_global_load_lds( \
    (const __attribute__((address_space(1))) unsigned int*)(g), \
    (__attribute__((address_space(3))) unsigned int*)(l), 16, 0, 0)

// Bank-conflict-free chunk rotation (rule #21): linear LDS dest, permuted
// global source chunk (c - (tid>>3))&3, matching permuted read rotation
// ((lk + (l16>>1))&3). Verified: conflict counter 9.17M -> 0.79M.

__device__ __forceinline__ u16 f2b(float v) {
  __bf16 h = (__bf16)v;
  return __builtin_bit_cast(u16, h);
}

// ---- P slice: f32 -> bf16 row-major (P) + bf16 transposed (PT) ----
__global__ void k_convP(const float* __restrict__ P, char* ws, int sliceBase) {
  __shared__ float tile[64][65];
  int s = blockIdx.z;
  const float* Ps = P + (size_t)(sliceBase + s) * NN * NN;
  char* base = ws + SLICE0 + (size_t)s * PS_BYTES;
  u16* Pb  = (u16*)(base + OFF_P);
  u16* PbT = (u16*)(base + OFF_PT);
  int r0 = blockIdx.y * 64, c0 = blockIdx.x * 64;
  int tid = threadIdx.x;
  int tc = tid & 15, tr = tid >> 4;
  for (int rr = 0; rr < 64; rr += 16) {
    int r = rr + tr;
    float4 v = *(const float4*)&Ps[(size_t)(r0 + r) * NN + c0 + tc * 4];
    tile[r][tc * 4 + 0] = v.x;
    tile[r][tc * 4 + 1] = v.y;
    tile[r][tc * 4 + 2] = v.z;
    tile[r][tc * 4 + 3] = v.w;
    u16x4 pk = {f2b(v.x), f2b(v.y), f2b(v.z), f2b(v.w)};
    *(u16x4*)&Pb[(size_t)(r0 + r) * NN + c0 + tc * 4] = pk;
  }
  __syncthreads();
  for (int it = 0; it < 4; ++it) {
    int oc = (tid >> 4) + it * 16;
    int ch = tid & 15;
    u16x4 pk = {f2b(tile[ch * 4 + 0][oc]), f2b(tile[ch * 4 + 1][oc]),
                f2b(tile[ch * 4 + 2][oc]), f2b(tile[ch * 4 + 3][oc])};
    *(u16x4*)&PbT[(size_t)(c0 + oc) * NN + r0 + ch * 4] = pk;
  }
}

// ---- X slice: f32 [1024][64] -> bf16 XT [64][1024] ----
__global__ void k_convX(const float* __restrict__ X, char* ws, int sliceBase) {
  __shared__ float tile[64][65];
  int s = blockIdx.z;
  const float* Xs = X + (size_t)(sliceBase + s) * NN * FF;
  u16* XT = (u16*)(ws + SLICE0 + (size_t)s * PS_BYTES + OFF_XT);
  int r0 = blockIdx.x * 64;
  int tx = threadIdx.x & 63, ty = threadIdx.x >> 6;
  for (int rr = 0; rr < 64; rr += 4)
    tile[rr + ty][tx] = Xs[(size_t)(r0 + rr + ty) * FF + tx];
  __syncthreads();
  for (int rr = 0; rr < 64; rr += 4)
    XT[(size_t)(rr + ty) * NN + r0 + tx] = f2b(tile[tx][rr + ty]);
}

__global__ void k_msum(const float* __restrict__ mask, float* msum) {
  int s = blockIdx.x;
  const float* m = mask + (size_t)s * NN;
  int t = threadIdx.x;
  float v = m[t] + m[t + 256] + m[t + 512] + m[t + 768];
  for (int o = 32; o; o >>= 1) v += __shfl_down(v, o);
  __shared__ float ps[4];
  if ((t & 63) == 0) ps[t >> 6] = v;
  __syncthreads();
  if (t == 0) msum[s] = ps[0] + ps[1] + ps[2] + ps[3];
}

// ---- squaring GEMM P2 = P @ P (B given transposed); r6-proven schedule:
// 128x128 tile, BK=32, 4 waves, dbuf, counted vmcnt(4), 32KB LDS.
__global__ __launch_bounds__(256)
void k_square(char* ws) {
  __shared__ u16 sh[16384];  // 32KB: A bufs @0/4096, B bufs @8192/12288

  unsigned nwg = gridDim.x, wg = blockIdx.x;
  unsigned newid = (wg & 7) * (nwg >> 3) + (wg >> 3);  // slice-per-XCD
  int z = newid >> 6;
  int by = (newid >> 3) & 7, bx = newid & 7;

  char* base = ws + SLICE0 + (size_t)z * PS_BYTES;
  const u16* A  = (const u16*)(base + OFF_P);
  const u16* Bt = (const u16*)(base + OFF_PT);
  u16* C        = (u16*)(base + OFF_P2);

  const int tid = threadIdx.x;
  const int lane = tid & 63, wave = tid >> 6;
  const int wr = wave >> 1, wc = wave & 1;
  const int l16 = lane & 15, lk = lane >> 4;
  const int bm = by * 128, bn = bx * 128;

  const int pc = (((tid & 3) - (tid >> 3)) & 3) << 3;
  const u16* gA = A + (size_t)(bm + (tid >> 2)) * NN + pc;
  const u16* gB = Bt + (size_t)(bn + (tid >> 2)) * NN + pc;
  const int rot = ((lk + (l16 >> 1)) & 3) << 3;

  f32x4 acc[4][4] = {};

#define SQ_STAGE(k0, buf)                                   \
  {                                                         \
    u16* dA = sh + (buf)*4096 + wave * 512;                 \
    u16* dB = sh + 8192 + (buf)*4096 + wave * 512;          \
    GL16(gA + (k0), dA);                                    \
    GL16(gA + 64 * NN + (k0), dA + 2048);                   \
    GL16(gB + (k0), dB);                                    \
    GL16(gB + 64 * NN + (k0), dB + 2048);                   \
  }

#define SQ_COMPUTE(buf)                                                      \
  {                                                                          \
    const u16* bA = sh + (buf)*4096;                                         \
    const u16* bB = sh + 8192 + (buf)*4096;                                  \
    bfx8 af[4], bf[4];                                                       \
    _Pragma("unroll") for (int m = 0; m < 4; ++m)                            \
        af[m] = *(const bfx8*)&bA[(wr * 64 + m * 16 + l16) * 32 + rot];      \
    _Pragma("unroll") for (int n = 0; n < 4; ++n)                            \
        bf[n] = *(const bfx8*)&bB[(wc * 64 + n * 16 + l16) * 32 + rot];      \
    __builtin_amdgcn_s_setprio(1);                                           \
    _Pragma("unroll") for (int m = 0; m < 4; ++m)                            \
        _Pragma("unroll") for (int n = 0; n < 4; ++n)                        \
            acc[m][n] = __builtin_amdgcn_mfma_f32_16x16x32_bf16(             \
                af[m], bf[n], acc[m][n], 0, 0, 0);                           \
    __builtin_amdgcn_s_setprio(0);                                           \
  }

  SQ_STAGE(0, 0);
#pragma unroll 2
  for (int t = 1; t < 32; ++t) {
    SQ_STAGE(t * 32, t & 1);
    asm volatile("s_waitcnt vmcnt(4)" ::: "memory");  // own tile t-1 done
    __builtin_amdgcn_s_barrier();                     // -> globally done
    SQ_COMPUTE((t - 1) & 1);
    __builtin_amdgcn_s_barrier();                     // reads done
  }
  asm volatile("s_waitcnt vmcnt(0)" ::: "memory");
  __builtin_amdgcn_s_barrier();
  SQ_COMPUTE(1);

  // C store (bf16 scalar)
#pragma unroll
  for (int m = 0; m < 4; ++m) {
    int row0 = bm + wr * 64 + m * 16 + lk * 4;
#pragma unroll
    for (int n = 0; n < 4; ++n) {
      int col = bn + wc * 64 + n * 16 + l16;
#pragma unroll
      for (int r = 0; r < 4; ++r)
        C[(size_t)(row0 + r) * NN + col] = f2b(acc[m][n][r]);
    }
  }
}

// ---- fused narrow GEMM: for one A[1024x1024], NB B-operands (Bt [64][1024])
// share the A staging: acc_j = A @ B_j. 64-row M-tiles (16 blocks/slice),
// 4 waves (2Mx2N), per-wave 32x32 per operand. Per-slot epilogue flags:
// d = f32 diff source, pk = pool-|w| feature idx, f = f32 out, ta = bf16-T
// of |w|, tv = bf16-T of v. rawK pools raw v of slot 0 (F0).
struct NA {
  int a, rawK;
  int bt[3], d[3], pk[3], f[3], ta[3], tv[3];
};

template <int NB>
__global__ __launch_bounds__(256)
void k_nar(char* ws, int sliceBase, float* __restrict__ pooled, NA na) {
  __shared__ u16 sh[16384];  // 32KB: buf b @ b*8192: A[2048] | B_j[2048]*3
  unsigned nwg = gridDim.x, wg = blockIdx.x;
  unsigned newid = (wg & 7) * (nwg >> 3) + (wg >> 3);  // slice-per-XCD
  int by = newid & 15;
  int s = newid >> 4;
  char* base = ws + SLICE0 + (size_t)s * PS_BYTES;

  const u16* A = (const u16*)(base + na.a);
  int poolBase = (sliceBase + s) * (KFEAT * FF);

  const int tid = threadIdx.x;
  const int lane = tid & 63, wave = tid >> 6;
  const int wr = wave >> 1, wc = wave & 1;
  const int l16 = lane & 15, lk = lane >> 4;
  const int bm = by * 64;

  const int pc = (((tid & 3) - (tid >> 3)) & 3) << 3;
  const u16* gA = A + (size_t)(bm + (tid >> 2)) * NN + pc;
  const u16* gB[NB];
#pragma unroll
  for (int j = 0; j < NB; ++j)
    gB[j] = (const u16*)(base + na.bt[j]) + (size_t)(tid >> 2) * NN + pc;
  const int rot = ((lk + (l16 >> 1)) & 3) << 3;

  f32x4 acc[NB][2][2] = {};

  auto STAGE = [&](int k0, int buf) {
    u16* dA = sh + buf * 8192 + wave * 512;
    GL16(gA + k0, dA);
#pragma unroll
    for (int j = 0; j < NB; ++j) {
      u16* dB = sh + buf * 8192 + 2048 + j * 2048 + wave * 512;
      GL16(gB[j] + k0, dB);
    }
  };
  auto COMPUTE = [&](int buf) {
    const u16* bA = sh + buf * 8192;
    bfx8 af[2];
#pragma unroll
    for (int m = 0; m < 2; ++m)
      af[m] = *(const bfx8*)&bA[(wr * 32 + m * 16 + l16) * 32 + rot];
    __builtin_amdgcn_s_setprio(1);
#pragma unroll
    for (int j = 0; j < NB; ++j) {
      const u16* bB = sh + buf * 8192 + 2048 + j * 2048;
      bfx8 bf[2];
#pragma unroll
      for (int n = 0; n < 2; ++n)
        bf[n] = *(const bfx8*)&bB[(wc * 32 + n * 16 + l16) * 32 + rot];
#pragma unroll
      for (int m = 0; m < 2; ++m)
#pragma unroll
        for (int n = 0; n < 2; ++n)
          acc[j][m][n] = __builtin_amdgcn_mfma_f32_16x16x32_bf16(
              af[m], bf[n], acc[j][m][n], 0, 0, 0);
    }
    __builtin_amdgcn_s_setprio(0);
  };

  STAGE(0, 0);
#pragma unroll 2
  for (int t = 1; t < 32; ++t) {
    STAGE(t * 32, t & 1);
    if constexpr (NB == 1)
      asm volatile("s_waitcnt vmcnt(2)" ::: "memory");
    else if constexpr (NB == 2)
      asm volatile("s_waitcnt vmcnt(3)" ::: "memory");
    else
      asm volatile("s_waitcnt vmcnt(4)" ::: "memory");
    __builtin_amdgcn_s_barrier();
    COMPUTE((t - 1) & 1);
    __builtin_amdgcn_s_barrier();
  }
  asm volatile("s_waitcnt vmcnt(0)" ::: "memory");
  __builtin_amdgcn_s_barrier();
  COMPUTE(1);

#pragma unroll
  for (int j = 0; j < NB; ++j) {
    const float* D = na.d[j] >= 0 ? (const float*)(base + na.d[j]) : nullptr;
    float* F  = na.f[j]  >= 0 ? (float*)(base + na.f[j])  : nullptr;
    u16* Ta   = na.ta[j] >= 0 ? (u16*)(base + na.ta[j])   : nullptr;
    u16* Tv   = na.tv[j] >= 0 ? (u16*)(base + na.tv[j])   : nullptr;
    bool doRaw = (j == 0) && (na.rawK >= 0);

    float ps[2] = {0.f, 0.f};
    float pr[2] = {0.f, 0.f};

#pragma unroll
    for (int m = 0; m < 2; ++m) {
      int row0 = bm + wr * 32 + m * 16 + lk * 4;
#pragma unroll
      for (int n = 0; n < 2; ++n) {
        int col = wc * 32 + n * 16 + l16;
        float v0 = acc[j][m][n][0], v1 = acc[j][m][n][1];
        float v2 = acc[j][m][n][2], v3 = acc[j][m][n][3];
        float w0 = v0, w1 = v1, w2 = v2, w3 = v3;
        if (D) {
          w0 = v0 - D[(size_t)(row0 + 0) * FF + col];
          w1 = v1 - D[(size_t)(row0 + 1) * FF + col];
          w2 = v2 - D[(size_t)(row0 + 2) * FF + col];
          w3 = v3 - D[(size_t)(row0 + 3) * FF + col];
        }
        float a0 = fabsf(w0), a1 = fabsf(w1), a2 = fabsf(w2), a3 = fabsf(w3);
        if (na.pk[j] >= 0) ps[n] += a0 + a1 + a2 + a3;
        if (doRaw) pr[n] += v0 + v1 + v2 + v3;
        if (F) {
          F[(size_t)(row0 + 0) * FF + col] = v0;
          F[(size_t)(row0 + 1) * FF + col] = v1;
          F[(size_t)(row0 + 2) * FF + col] = v2;
          F[(size_t)(row0 + 3) * FF + col] = v3;
        }
        if (Ta) {
          u16x4 pkk = {f2b(a0), f2b(a1), f2b(a2), f2b(a3)};
          *(u16x4*)&Ta[(size_t)col * NN + row0] = pkk;
        }
        if (Tv) {
          u16x4 pkk = {f2b(v0), f2b(v1), f2b(v2), f2b(v3)};
          *(u16x4*)&Tv[(size_t)col * NN + row0] = pkk;
        }
      }
    }

    if (na.pk[j] >= 0) {
#pragma unroll
      for (int n = 0; n < 2; ++n) {
        float v = ps[n];
        v += __shfl_xor(v, 16);
        v += __shfl_xor(v, 32);
        if (lane < 16)
          atomicAdd(&pooled[poolBase + na.pk[j] * FF + wc * 32 + n * 16 + lane], v);
      }
    }
    if (doRaw) {
#pragma unroll
      for (int n = 0; n < 2; ++n) {
        float v = pr[n];
        v += __shfl_xor(v, 16);
        v += __shfl_xor(v, 32);
        if (lane < 16)
          atomicAdd(&pooled[poolBase + na.rawK * FF + wc * 32 + n * 16 + lane], v);
      }
    }
  }
}

__global__ void k_final(const float* __restrict__ pooled, const float* __restrict__ msum,
                        float* __restrict__ out, int total) {
  int i = blockIdx.x * 256 + threadIdx.x;
  if (i < total) out[i] = pooled[i] / msum[i / (KFEAT * FF)];
}

// helper: one-slot NA
static NA mk1(int a, int rawK, int bt, int d, int pk, int f, int ta, int tv) {
  NA x;
  x.a = a; x.rawK = rawK;
  for (int j = 0; j < 3; ++j) {
    x.bt[j] = -1; x.d[j] = -1; x.pk[j] = -1;
    x.f[j] = -1; x.ta[j] = -1; x.tv[j] = -1;
  }
  x.bt[0] = bt; x.d[0] = d; x.pk[0] = pk; x.f[0] = f; x.ta[0] = ta; x.tv[0] = tv;
  return x;
}
static void setslot(NA& x, int j, int bt, int d, int pk, int f, int ta, int tv) {
  x.bt[j] = bt; x.d[j] = d; x.pk[j] = pk; x.f[j] = f; x.ta[j] = ta; x.tv[j] = tv;
}

extern "C" void kernel_launch(void* const* d_in, const int* in_sizes, int n_in,
                              void* d_out, int out_size, void* d_ws, size_t ws_size,
                              hipStream_t stream) {
  const float* P = (const float*)d_in[0];
  const float* X = (const float*)d_in[1];
  const float* mask = (const float*)d_in[2];
  float* out = (float*)d_out;
  char* ws = (char*)d_ws;
  float* pooled = (float*)ws;
  float* msum = (float*)(ws + MSUM_OFF);

  hipMemsetAsync(pooled, 0, POOL_BYTES, stream);
  k_msum<<<NSLICE, 256, 0, stream>>>(mask, msum);

  int S = 1;
  if (ws_size > SLICE0 + PS_BYTES) S = (int)((ws_size - SLICE0) / PS_BYTES);
  if (S > NSLICE) S = NSLICE;
  if (S < 1) S = 1;

  for (int b0 = 0; b0 < NSLICE; b0 += S) {
    int n = (NSLICE - b0 < S) ? (NSLICE - b0) : S;
    k_convP<<<dim3(16, 16, n), 256, 0, stream>>>(P, ws, b0);
    k_convX<<<dim3(16, 1, n), 256, 0, stream>>>(X, ws, b0);
    // single squaring: P2 = P @ P
    k_square<<<64 * n, 256, 0, stream>>>(ws);

    // ---- Y chain by P2 hops ----
    // c1: Y1 = P X (f32)
    NA c1 = mk1(OFF_P, -1, OFF_XT, -1, -1, OFF_Y1, -1, -1);
    k_nar<1><<<16 * n, 256, 0, stream>>>(ws, b0, pooled, c1);
    // c2: Y2 = P2 X ; s0=|Y2-Y1| pool1 ; Y2 f32 + Y2T
    NA c2 = mk1(OFF_P2, -1, OFF_XT, (int)OFF_Y1, 1, OFF_Y2, -1, OFF_Y2T);
    k_nar<1><<<16 * n, 256, 0, stream>>>(ws, b0, pooled, c2);
    // c3: Y4 = P2 Y2 ; s1=|Y4-Y2| pool2 + S1T ; Y4 f32 + Y4T
    NA c3 = mk1(OFF_P2, -1, OFF_Y2T, (int)OFF_Y2, 2, OFF_Y4, OFF_S1T, OFF_Y4T);
    k_nar<1><<<16 * n, 256, 0, stream>>>(ws, b0, pooled, c3);
    // c4: Y6 = P2 Y4 -> Y6T
    NA c4 = mk1(OFF_P2, -1, OFF_Y4T, -1, -1, -1, -1, OFF_Y6T);
    k_nar<1><<<16 * n, 256, 0, stream>>>(ws, b0, pooled, c4);
    // c5: Y8 = P2 Y6 ; s2=|Y8-Y4| pool3 + S2T ; Y8 f32 + Y8T
    NA c5 = mk1(OFF_P2, -1, OFF_Y6T, (int)OFF_Y4, 3, OFF_Y8, OFF_S2T, OFF_Y8T);
    k_nar<1><<<16 * n, 256, 0, stream>>>(ws, b0, pooled, c5);
    // c6-c8: Y10, Y12, Y14 (T only)
    NA c6 = mk1(OFF_P2, -1, OFF_Y8T, -1, -1, -1, -1, OFF_Y10T);
    k_nar<1><<<16 * n, 256, 0, stream>>>(ws, b0, pooled, c6);
    NA c7 = mk1(OFF_P2, -1, OFF_Y10T, -1, -1, -1, -1, OFF_Y12T);
    k_nar<1><<<16 * n, 256, 0, stream>>>(ws, b0, pooled, c7);
    NA c8 = mk1(OFF_P2, -1, OFF_Y12T, -1, -1, -1, -1, OFF_Y14T);
    k_nar<1><<<16 * n, 256, 0, stream>>>(ws, b0, pooled, c8);
    // c9: Y16 = P2 Y14 ; s3=|Y16-Y8| pool4 + S3T ; F0 raw pool0
    NA c9 = mk1(OFF_P2, 0, OFF_Y14T, (int)OFF_Y8, 4, -1, OFF_S3T, -1);
    k_nar<1><<<16 * n, 256, 0, stream>>>(ws, b0, pooled, c9);

    // ---- second order ----
    // c10 (fused): P * {s1,s2,s3} -> PS1,PS2,PS3
    NA c10 = mk1(OFF_P, -1, OFF_S1T, -1, -1, OFF_PS1, -1, -1);
    setslot(c10, 1, OFF_S2T, -1, -1, OFF_PS2, -1, -1);
    setslot(c10, 2, OFF_S3T, -1, -1, OFF_PS3, -1, -1);
    k_nar<3><<<16 * n, 256, 0, stream>>>(ws, b0, pooled, c10);
    // c11 (fused): P2 * {s1,s2,s3} ; pools 5,6,8 = |P2 s_i - P s_i| ;
    //   keep QS2,QS3 f32 + their T for the P4 hop
    NA c11 = mk1(OFF_P2, -1, OFF_S1T, (int)OFF_PS1, 5, -1, -1, -1);
    setslot(c11, 1, OFF_S2T, (int)OFF_PS2, 6, OFF_QS2, -1, OFF_TQ2);
    setslot(c11, 2, OFF_S3T, (int)OFF_PS3, 8, OFF_QS3, -1, OFF_TQ3);
    k_nar<3><<<16 * n, 256, 0, stream>>>(ws, b0, pooled, c11);
    // c12 (fused): P2 * {TQ2,TQ3} = {P4s2, P4s3} ; pools 7,9 ; W4 f32 + TW4
    NA c12 = mk1(OFF_P2, -1, OFF_TQ2, (int)OFF_QS2, 7, -1, -1, -1);
    setslot(c12, 1, OFF_TQ3, (int)OFF_QS3, 9, OFF_W4, -1, OFF_TW4);
    k_nar<2><<<16 * n, 256, 0, stream>>>(ws, b0, pooled, c12);
    // c13: P6s3 = P2 * TW4 -> TP6
    NA c13 = mk1(OFF_P2, -1, OFF_TW4, -1, -1, -1, -1, OFF_TP6);
    k_nar<1><<<16 * n, 256, 0, stream>>>(ws, b0, pooled, c13);
    // c14: P8s3 = P2 * TP6 ; pool10 = |P8s3 - P4s3|
    NA c14 = mk1(OFF_P2, -1, OFF_TP6, (int)OFF_W4, 10, -1, -1, -1);
    k_nar<1><<<16 * n, 256, 0, stream>>>(ws, b0, pooled, c14);
  }
  int total = NSLICE * KFEAT * FF;
  k_final<<<(total + 255) / 256, 256, 0, stream>>>(pooled, msum, out, total);
}